// Round 7
// baseline (579.468 us; speedup 1.0000x reference)
//
#include <hip/hip_runtime.h>
#include <math.h>

#define HH    48
#define CFEAT 512
#define HID   256
#define NPOS  (HH*HH)   // 2304
#define TQ    32        // queries per block
#define NEV   128       // evals per block = TQ*4
#define ACTP  264       // padded act row (bf16): 528B stride, rows 16B-aligned

typedef __attribute__((ext_vector_type(8))) short bf16x8;
typedef __attribute__((ext_vector_type(4))) float f32x4;

static __device__ __forceinline__ unsigned short f2bf(float x) {
  unsigned int u = __float_as_uint(x);
  u += 0x7fffu + ((u >> 16) & 1u);     // RNE
  return (unsigned short)(u >> 16);
}
static __device__ __forceinline__ float bf2f(unsigned short h) {
  return __uint_as_float(((unsigned int)h) << 16);
}

// ---------------------------------------------------------------------------
// Kernel 1: P[b][pos][n] = b0[n] + sum_c feat[b][c][pos] * W0[c][n]  (fp32)
// ---------------------------------------------------------------------------
__global__ __launch_bounds__(256) void liif_precompute(
    const float* __restrict__ feat, const float* __restrict__ W0,
    const float* __restrict__ b0, float* __restrict__ P)
{
  int blk = blockIdx.x;                 // 0..1151
  int b   = blk / (NPOS/4);
  int p0  = (blk - b*(NPOS/4)) * 4;
  int n   = threadIdx.x;
  const float* f = feat + (size_t)b * CFEAT * NPOS + p0;
  float bias = b0[n];
  float a0 = bias, a1 = bias, a2 = bias, a3 = bias;
  #pragma unroll 4
  for (int c = 0; c < CFEAT; ++c) {
    float w = W0[c*HID + n];
    const float* fr = f + (size_t)c * NPOS;
    a0 += fr[0]*w; a1 += fr[1]*w; a2 += fr[2]*w; a3 += fr[3]*w;
  }
  float* Pp = P + ((size_t)b*NPOS + p0)*HID + n;
  Pp[0*HID] = a0; Pp[1*HID] = a1; Pp[2*HID] = a2; Pp[3*HID] = a3;
}

// ---------------------------------------------------------------------------
// Kernel 2: transpose+convert W1..W3 -> bf16 Wt[l][n][k]; W4 -> f32 W4t[o][k]
// ---------------------------------------------------------------------------
__global__ __launch_bounds__(256) void liif_convert(
    const float* __restrict__ W1, const float* __restrict__ W2,
    const float* __restrict__ W3, const float* __restrict__ W4,
    unsigned short* __restrict__ wt, float* __restrict__ w4t)
{
  int b = blockIdx.x, t = threadIdx.x;
  if (b < 768) {
    int l = b >> 8, n = b & 255;
    const float* W = (l == 0) ? W1 : (l == 1) ? W2 : W3;
    wt[l*65536 + n*256 + t] = f2bf(W[t*256 + n]);   // Wt[n][k] = W[k][n]
  } else {
    for (int o = 0; o < 3; ++o) w4t[o*256 + t] = W4[t*3 + o];
  }
}

// ---------------------------------------------------------------------------
// Kernel 3: fused main. 128 evals/block, 8 waves (2x4), wave = 64x64 tile.
// W streamed from L2 with depth-2 even/odd named-register prefetch;
// act from LDS; final layer fused into layer-3 accumulators.
// ---------------------------------------------------------------------------

#define LDW(WT, KC, NT) \
  (*(const bf16x8*)&(WT)[(size_t)(nW + (NT)*16 + lr)*256 + (KC)*32 + lk*8])
#define LDA(KC, MT) \
  (*(const bf16x8*)&act[(m0 + (MT)*16 + lr)*ACTP + (KC)*32 + lk*8])
#define MF(A, B, C) __builtin_amdgcn_mfma_f32_16x16x32_bf16((A), (B), (C), 0, 0, 0)

// MFMA body for one layer: depth-2 W prefetch, fills acc[16], then syncs.
#define LAYER_MM(WT) do {                                                     \
    _Pragma("unroll")                                                         \
    for (int i_ = 0; i_ < 16; ++i_) acc[i_] = (f32x4){0.f, 0.f, 0.f, 0.f};    \
    bf16x8 e0_ = LDW(WT, 0, 0), e1_ = LDW(WT, 0, 1);                          \
    bf16x8 e2_ = LDW(WT, 0, 2), e3_ = LDW(WT, 0, 3);                          \
    bf16x8 o0_ = LDW(WT, 1, 0), o1_ = LDW(WT, 1, 1);                          \
    bf16x8 o2_ = LDW(WT, 1, 2), o3_ = LDW(WT, 1, 3);                          \
    _Pragma("unroll")                                                         \
    for (int kc_ = 0; kc_ < 8; ++kc_) {                                       \
      bf16x8 w0_, w1_, w2_, w3_;                                              \
      if (kc_ & 1) { w0_ = o0_; w1_ = o1_; w2_ = o2_; w3_ = o3_; }            \
      else         { w0_ = e0_; w1_ = e1_; w2_ = e2_; w3_ = e3_; }            \
      if (kc_ < 6) {                 /* issue kc+2 into the freed set */      \
        if (kc_ & 1) { o0_ = LDW(WT, kc_+2, 0); o1_ = LDW(WT, kc_+2, 1);      \
                       o2_ = LDW(WT, kc_+2, 2); o3_ = LDW(WT, kc_+2, 3); }    \
        else         { e0_ = LDW(WT, kc_+2, 0); e1_ = LDW(WT, kc_+2, 1);      \
                       e2_ = LDW(WT, kc_+2, 2); e3_ = LDW(WT, kc_+2, 3); }    \
      }                                                                       \
      bf16x8 a0_ = LDA(kc_, 0), a1_ = LDA(kc_, 1);                            \
      bf16x8 a2_ = LDA(kc_, 2), a3_ = LDA(kc_, 3);                            \
      acc[0]  = MF(w0_, a0_, acc[0]);  acc[1]  = MF(w1_, a0_, acc[1]);        \
      acc[2]  = MF(w2_, a0_, acc[2]);  acc[3]  = MF(w3_, a0_, acc[3]);        \
      acc[4]  = MF(w0_, a1_, acc[4]);  acc[5]  = MF(w1_, a1_, acc[5]);        \
      acc[6]  = MF(w2_, a1_, acc[6]);  acc[7]  = MF(w3_, a1_, acc[7]);        \
      acc[8]  = MF(w0_, a2_, acc[8]);  acc[9]  = MF(w1_, a2_, acc[9]);        \
      acc[10] = MF(w2_, a2_, acc[10]); acc[11] = MF(w3_, a2_, acc[11]);       \
      acc[12] = MF(w0_, a3_, acc[12]); acc[13] = MF(w1_, a3_, acc[13]);       \
      acc[14] = MF(w2_, a3_, acc[14]); acc[15] = MF(w3_, a3_, acc[15]);       \
    }                                                                         \
    __syncthreads();  /* all act reads of this layer done */                  \
  } while (0)

// bias+relu -> bf16 writeback to act (D[n][m]: lane m-col = lr, n = lk*4+j)
#define LAYER_WB(BIAS) do {                                                   \
    _Pragma("unroll")                                                         \
    for (int nt_ = 0; nt_ < 4; ++nt_) {                                       \
      f32x4 bv_ = *(const f32x4*)&(BIAS)[nW + nt_*16 + lk*4];                 \
      _Pragma("unroll")                                                       \
      for (int mt_ = 0; mt_ < 4; ++mt_) {                                     \
        f32x4 a_ = acc[mt_*4 + nt_];                                          \
        unsigned int lo_ = (unsigned int)f2bf(fmaxf(a_[0] + bv_[0], 0.f))     \
                         | ((unsigned int)f2bf(fmaxf(a_[1] + bv_[1], 0.f)) << 16); \
        unsigned int hi_ = (unsigned int)f2bf(fmaxf(a_[2] + bv_[2], 0.f))     \
                         | ((unsigned int)f2bf(fmaxf(a_[3] + bv_[3], 0.f)) << 16); \
        *(uint2*)&act[(m0 + mt_*16 + lr)*ACTP + nW + nt_*16 + lk*4] =         \
            make_uint2(lo_, hi_);                                             \
      }                                                                       \
    }                                                                         \
    __syncthreads();  /* writeback visible before next layer's reads */      \
  } while (0)

__global__ __launch_bounds__(512, 4)
__attribute__((amdgpu_waves_per_eu(4, 4)))
void liif_main(
    const float* __restrict__ coord, const float* __restrict__ cell,
    const float* __restrict__ P,  const float* __restrict__ W0,
    const unsigned short* __restrict__ wt,
    const float* __restrict__ b1, const float* __restrict__ b2,
    const float* __restrict__ b3, const float* __restrict__ b4,
    const float* __restrict__ w4t, float* __restrict__ out)
{
  __shared__ __align__(16) unsigned short act[NEV*ACTP];   // 67.6 KB
  __shared__ int   lin_s[NEV];
  __shared__ float r0_s[NEV], r1_s[NEV], rc0_s[NEV], rc1_s[NEV], area_s[NEV];
  float* predp = (float*)act;           // overlay: [4 wc][128 m][3 o] = 6 KB

  const int t   = threadIdx.x;
  const int blk = blockIdx.x;
  const int b   = blk >> 11;            // 2048 blocks per batch
  const int q0  = (blk & 2047) * TQ;

  const int lane = t & 63;
  const int w    = t >> 6;              // 0..7
  const int m0   = (w >> 2) * 64;       // wave row base (0 / 64)
  const int nW   = (w & 3) * 64;        // wave col base (0/64/128/192)
  const int lr   = lane & 15;
  const int lk   = lane >> 4;

  // ---- Phase A: indices, rel coords, areas (bit-exact vs numpy fp32) ------
  if (t < NEV) {
    const int e = t;
    const int q = q0 + (e >> 2);
    const int s = e & 3;                // [(-1,-1),(-1,1),(1,-1),(1,1)]
    const size_t cbase = (((size_t)b << 16) + q) * 2;
    float c0 = coord[cbase + 0];
    float c1 = coord[cbase + 1];
    float vx = (s & 2) ? 1.0f : -1.0f;
    float vy = (s & 1) ? 1.0f : -1.0f;
    const float RXY = (float)(1.0/48.0);
    const float CLO = (float)(-1.0 + 1e-6);
    const float CHI = (float)( 1.0 - 1e-6);
    float gx = __fadd_rn(c0, __fadd_rn(__fmul_rn(vx, RXY), 1e-6f));
    float gy = __fadd_rn(c1, __fadd_rn(__fmul_rn(vy, RXY), 1e-6f));
    gx = fminf(fmaxf(gx, CLO), CHI);
    gy = fminf(fmaxf(gy, CLO), CHI);
    float xr = __fmul_rn(__fsub_rn(__fmul_rn(__fadd_rn(gx, 1.0f), 48.0f), 1.0f), 0.5f);
    float xc = __fmul_rn(__fsub_rn(__fmul_rn(__fadd_rn(gy, 1.0f), 48.0f), 1.0f), 0.5f);
    int ir = (int)rintf(xr); ir = ir < 0 ? 0 : (ir > HH-1 ? HH-1 : ir);
    int ic = (int)rintf(xc); ic = ic < 0 ? 0 : (ic > HH-1 ? HH-1 : ic);
    lin_s[e] = ir*HH + ic;
    const float T2 = (float)(2.0/48.0);
    float qcr = __fsub_rn(__fmul_rn(__fadd_rn((float)ir, 0.5f), T2), 1.0f);
    float qcc = __fsub_rn(__fmul_rn(__fadd_rn((float)ic, 0.5f), T2), 1.0f);
    float r0 = __fmul_rn(__fsub_rn(c0, qcr), 48.0f);
    float r1 = __fmul_rn(__fsub_rn(c1, qcc), 48.0f);
    r0_s[e] = r0; r1_s[e] = r1;
    area_s[e] = __fadd_rn(fabsf(__fmul_rn(r0, r1)), 1e-9f);
    rc0_s[e] = __fmul_rn(cell[cbase + 0], 48.0f);
    rc1_s[e] = __fmul_rn(cell[cbase + 1], 48.0f);
  }
  __syncthreads();

  // ---- Phase B: h0 -> bf16 act. 512 thr: 128 col-pairs x 4 row-quarters ---
  {
    const int c2 = (t & 127) * 2;       // column pair
    const int rq = t >> 7;              // row quarter
    float wA = W0[(size_t)512*HID + c2],  wBv = W0[(size_t)512*HID + c2 + 1];
    float xA = W0[(size_t)513*HID + c2],  xB = W0[(size_t)513*HID + c2 + 1];
    float yA = W0[(size_t)514*HID + c2],  yB = W0[(size_t)514*HID + c2 + 1];
    float zA = W0[(size_t)515*HID + c2],  zB = W0[(size_t)515*HID + c2 + 1];
    const float* Pb = P + (size_t)b * NPOS * HID;
    #pragma unroll 4
    for (int i = 0; i < 32; ++i) {
      const int e = rq*32 + i;
      const float* pr = Pb + (size_t)lin_s[e]*HID + c2;
      float vA = pr[0] + r0_s[e]*wA + r1_s[e]*xA + rc0_s[e]*yA + rc1_s[e]*zA;
      float vB = pr[1] + r0_s[e]*wBv + r1_s[e]*xB + rc0_s[e]*yB + rc1_s[e]*zB;
      unsigned int pk = (unsigned int)f2bf(fmaxf(vA, 0.0f)) |
                        ((unsigned int)f2bf(fmaxf(vB, 0.0f)) << 16);
      *(unsigned int*)&act[e*ACTP + c2] = pk;
    }
  }
  __syncthreads();                      // act (h0) ready

  f32x4 acc[16];
  LAYER_MM(wt);              LAYER_WB(b1);   // layer 1
  LAYER_MM(wt + 65536);      LAYER_WB(b2);   // layer 2
  LAYER_MM(wt + 131072);                     // layer 3 (ends with barrier)

  // ---- fused final layer: p[mt][o] = sum_n relu(acc+b3) * W4t[o][n] -------
  {
    float p[4][3];
    #pragma unroll
    for (int mt = 0; mt < 4; ++mt)
      { p[mt][0] = 0.f; p[mt][1] = 0.f; p[mt][2] = 0.f; }
    #pragma unroll
    for (int nt = 0; nt < 4; ++nt) {
      f32x4 bv = *(const f32x4*)&b3[nW + nt*16 + lk*4];
      f32x4 w40 = *(const f32x4*)&w4t[      nW + nt*16 + lk*4];
      f32x4 w41 = *(const f32x4*)&w4t[256 + nW + nt*16 + lk*4];
      f32x4 w42 = *(const f32x4*)&w4t[512 + nW + nt*16 + lk*4];
      #pragma unroll
      for (int mt = 0; mt < 4; ++mt) {
        f32x4 a = acc[mt*4 + nt];
        #pragma unroll
        for (int j = 0; j < 4; ++j) {
          float v = fmaxf(a[j] + bv[j], 0.f);
          p[mt][0] += v * w40[j];
          p[mt][1] += v * w41[j];
          p[mt][2] += v * w42[j];
        }
      }
    }
    // reduce over lk groups (lanes 16/32 apart hold other n-subranges)
    #pragma unroll
    for (int mt = 0; mt < 4; ++mt)
      #pragma unroll
      for (int o = 0; o < 3; ++o) {
        float s = p[mt][o];
        s += __shfl_xor(s, 16);
        s += __shfl_xor(s, 32);
        p[mt][o] = s;
      }
    if (lk == 0) {                       // lanes 0..15: one writer per m-col
      #pragma unroll
      for (int mt = 0; mt < 4; ++mt) {
        const int m = m0 + mt*16 + lr;
        predp[(w & 3)*384 + m*3 + 0] = p[mt][0];
        predp[(w & 3)*384 + m*3 + 1] = p[mt][1];
        predp[(w & 3)*384 + m*3 + 2] = p[mt][2];
      }
    }
  }
  __syncthreads();

  // ---- blend: pred[e][o] = b4 + sum_wc partials; w[s] = area[3-s]/tot -----
  if (t < TQ*3) {
    const int q = t / 3, o = t - (t/3)*3;
    const int eb = q*4;
    float pe[4];
    #pragma unroll
    for (int s = 0; s < 4; ++s) {
      const int e = eb + s;
      pe[s] = b4[o] + predp[e*3 + o] + predp[384 + e*3 + o]
                    + predp[768 + e*3 + o] + predp[1152 + e*3 + o];
    }
    float a0 = area_s[eb+0], a1 = area_s[eb+1], a2 = area_s[eb+2], a3 = area_s[eb+3];
    float tot = ((a0 + a1) + a2) + a3;
    float rv = (pe[0]*a3 + pe[1]*a2 + pe[2]*a1 + pe[3]*a0) / tot;
    out[(((size_t)b << 16) + (q0 + q))*3 + o] = rv;
  }
}

// ---------------------------------------------------------------------------
extern "C" void kernel_launch(void* const* d_in, const int* in_sizes, int n_in,
                              void* d_out, int out_size, void* d_ws, size_t ws_size,
                              hipStream_t stream)
{
  const float* feat  = (const float*)d_in[0];
  const float* coord = (const float*)d_in[1];
  const float* cell  = (const float*)d_in[2];
  const float* W0    = (const float*)d_in[3];
  const float* b0    = (const float*)d_in[4];
  const float* W1    = (const float*)d_in[5];
  const float* b1    = (const float*)d_in[6];
  const float* W2    = (const float*)d_in[7];
  const float* b2    = (const float*)d_in[8];
  const float* W3    = (const float*)d_in[9];
  const float* b3    = (const float*)d_in[10];
  const float* W4    = (const float*)d_in[11];
  const float* b4    = (const float*)d_in[12];
  float* outp = (float*)d_out;

  // ws layout: P f32 [2*2304*256] = 4,718,592 B | Wt bf16 3*64K = 393,216 B
  //            | W4t f32 3*256 = 3,072 B
  float*          P    = (float*)d_ws;
  unsigned short* wtp  = (unsigned short*)((char*)d_ws + 4718592);
  float*          w4tp = (float*)((char*)d_ws + 4718592 + 393216);

  hipLaunchKernelGGL(liif_precompute, dim3(2*(NPOS/4)), dim3(256), 0, stream,
                     feat, W0, b0, P);
  hipLaunchKernelGGL(liif_convert, dim3(769), dim3(256), 0, stream,
                     W1, W2, W3, W4, wtp, w4tp);
  hipLaunchKernelGGL(liif_main, dim3(4096), dim3(512), 0, stream,
                     coord, cell, P, W0, wtp, b1, b2, b3, b4, w4tp, outp);
}

// Round 8
// 526.160 us; speedup vs baseline: 1.1013x; 1.1013x over previous
//
#include <hip/hip_runtime.h>
#include <math.h>

#define HH    48
#define CFEAT 512
#define HID   256
#define NPOS  (HH*HH)   // 2304
#define TQ    32        // queries per block
#define NEV   128       // evals per block = TQ*4
#define ACTP  264       // padded act row (bf16): 528B stride, rows 16B-aligned

typedef __attribute__((ext_vector_type(8))) short bf16x8;
typedef __attribute__((ext_vector_type(4))) float f32x4;

static __device__ __forceinline__ unsigned short f2bf(float x) {
  unsigned int u = __float_as_uint(x);
  u += 0x7fffu + ((u >> 16) & 1u);     // RNE
  return (unsigned short)(u >> 16);
}
static __device__ __forceinline__ float bf2f(unsigned short h) {
  return __uint_as_float(((unsigned int)h) << 16);
}

// ---------------------------------------------------------------------------
// Kernel 1: P[b][pos][n] = b0[n] + sum_c feat[b][c][pos] * W0[c][n]  (fp32)
// ---------------------------------------------------------------------------
__global__ __launch_bounds__(256) void liif_precompute(
    const float* __restrict__ feat, const float* __restrict__ W0,
    const float* __restrict__ b0, float* __restrict__ P)
{
  int blk = blockIdx.x;                 // 0..1151
  int b   = blk / (NPOS/4);
  int p0  = (blk - b*(NPOS/4)) * 4;
  int n   = threadIdx.x;
  const float* f = feat + (size_t)b * CFEAT * NPOS + p0;
  float bias = b0[n];
  float a0 = bias, a1 = bias, a2 = bias, a3 = bias;
  #pragma unroll 4
  for (int c = 0; c < CFEAT; ++c) {
    float w = W0[c*HID + n];
    const float* fr = f + (size_t)c * NPOS;
    a0 += fr[0]*w; a1 += fr[1]*w; a2 += fr[2]*w; a3 += fr[3]*w;
  }
  float* Pp = P + ((size_t)b*NPOS + p0)*HID + n;
  Pp[0*HID] = a0; Pp[1*HID] = a1; Pp[2*HID] = a2; Pp[3*HID] = a3;
}

// ---------------------------------------------------------------------------
// Kernel 2: transpose+convert W1..W3 -> bf16 Wt[l][n][k]; W4 -> f32 W4t[o][k]
// ---------------------------------------------------------------------------
__global__ __launch_bounds__(256) void liif_convert(
    const float* __restrict__ W1, const float* __restrict__ W2,
    const float* __restrict__ W3, const float* __restrict__ W4,
    unsigned short* __restrict__ wt, float* __restrict__ w4t)
{
  int b = blockIdx.x, t = threadIdx.x;
  if (b < 768) {
    int l = b >> 8, n = b & 255;
    const float* W = (l == 0) ? W1 : (l == 1) ? W2 : W3;
    wt[l*65536 + n*256 + t] = f2bf(W[t*256 + n]);   // Wt[n][k] = W[k][n]
  } else {
    for (int o = 0; o < 3; ++o) w4t[o*256 + t] = W4[t*3 + o];
  }
}

// ---------------------------------------------------------------------------
// Kernel 3: fused main. 128 evals/block, 8 waves (2x4), wave = 64x64 tile.
// Double-buffered act in LDS (one barrier per LAYER, no per-chunk barriers).
// W streamed from L2 in half-layer register groups (g0/g1, 64 regs each);
// 256-reg budget via waves_per_eu(2,2). Final layer fused into accumulators.
// ---------------------------------------------------------------------------

#define LDW2(WT, KC, NT) \
  (*(const bf16x8*)&(WT)[(size_t)(nW + (NT)*16 + lr)*256 + (KC)*32 + lk*8])

// load 4 K-chunks (KC0..KC0+3) x 4 n-frags into DST[16]
#define LOADG(DST, WT, KC0) do {                                              \
    _Pragma("unroll")                                                         \
    for (int q_ = 0; q_ < 4; ++q_) {                                          \
      _Pragma("unroll")                                                       \
      for (int nt_ = 0; nt_ < 4; ++nt_)                                       \
        DST[q_*4 + nt_] = LDW2(WT, (KC0) + q_, nt_);                          \
    }                                                                         \
  } while (0)

#define LDAB(BIN, KC, MT) \
  (*(const bf16x8*)&(BIN)[(m0 + (MT)*16 + lr)*ACTP + (KC)*32 + lk*8])
#define MF(A, B, C) __builtin_amdgcn_mfma_f32_16x16x32_bf16((A), (B), (C), 0, 0, 0)

// one K-chunk (K=32): 4 act reads + 16 MFMA, W from WSET[Q*4 + nt]
#define QCHUNK(BIN, WSET, Q, KC) do {                                         \
    bf16x8 a0_ = LDAB(BIN, KC, 0), a1_ = LDAB(BIN, KC, 1);                    \
    bf16x8 a2_ = LDAB(BIN, KC, 2), a3_ = LDAB(BIN, KC, 3);                    \
    acc[0]  = MF(WSET[(Q)*4+0], a0_, acc[0]);                                 \
    acc[1]  = MF(WSET[(Q)*4+1], a0_, acc[1]);                                 \
    acc[2]  = MF(WSET[(Q)*4+2], a0_, acc[2]);                                 \
    acc[3]  = MF(WSET[(Q)*4+3], a0_, acc[3]);                                 \
    acc[4]  = MF(WSET[(Q)*4+0], a1_, acc[4]);                                 \
    acc[5]  = MF(WSET[(Q)*4+1], a1_, acc[5]);                                 \
    acc[6]  = MF(WSET[(Q)*4+2], a1_, acc[6]);                                 \
    acc[7]  = MF(WSET[(Q)*4+3], a1_, acc[7]);                                 \
    acc[8]  = MF(WSET[(Q)*4+0], a2_, acc[8]);                                 \
    acc[9]  = MF(WSET[(Q)*4+1], a2_, acc[9]);                                 \
    acc[10] = MF(WSET[(Q)*4+2], a2_, acc[10]);                                \
    acc[11] = MF(WSET[(Q)*4+3], a2_, acc[11]);                                \
    acc[12] = MF(WSET[(Q)*4+0], a3_, acc[12]);                                \
    acc[13] = MF(WSET[(Q)*4+1], a3_, acc[13]);                                \
    acc[14] = MF(WSET[(Q)*4+2], a3_, acc[14]);                                \
    acc[15] = MF(WSET[(Q)*4+3], a3_, acc[15]);                                \
  } while (0)

// full layer matmul: in BIN; W for chunks 0-3 already in g0.
// Loads chunks 4-7 into g1, computes 0-3, optionally preloads next layer's
// chunks 0-3 into g0, computes 4-7. No barriers inside.
#define LAYER_MM2(BIN, WT, WNXT, DONEXT) do {                                 \
    _Pragma("unroll")                                                         \
    for (int i_ = 0; i_ < 16; ++i_) acc[i_] = (f32x4){0.f, 0.f, 0.f, 0.f};    \
    LOADG(g1, WT, 4);                                                         \
    QCHUNK(BIN, g0, 0, 0);                                                    \
    QCHUNK(BIN, g0, 1, 1);                                                    \
    QCHUNK(BIN, g0, 2, 2);                                                    \
    QCHUNK(BIN, g0, 3, 3);                                                    \
    if (DONEXT) LOADG(g0, WNXT, 0);                                           \
    QCHUNK(BIN, g1, 0, 4);                                                    \
    QCHUNK(BIN, g1, 1, 5);                                                    \
    QCHUNK(BIN, g1, 2, 6);                                                    \
    QCHUNK(BIN, g1, 3, 7);                                                    \
  } while (0)

// bias+relu -> bf16 writeback to BOUT (other buffer), then one barrier
#define LAYER_WB2(BOUT, BIAS) do {                                            \
    _Pragma("unroll")                                                         \
    for (int nt_ = 0; nt_ < 4; ++nt_) {                                       \
      f32x4 bv_ = *(const f32x4*)&(BIAS)[nW + nt_*16 + lk*4];                 \
      _Pragma("unroll")                                                       \
      for (int mt_ = 0; mt_ < 4; ++mt_) {                                     \
        f32x4 a_ = acc[mt_*4 + nt_];                                          \
        unsigned int lo_ = (unsigned int)f2bf(fmaxf(a_[0] + bv_[0], 0.f))     \
                         | ((unsigned int)f2bf(fmaxf(a_[1] + bv_[1], 0.f)) << 16); \
        unsigned int hi_ = (unsigned int)f2bf(fmaxf(a_[2] + bv_[2], 0.f))     \
                         | ((unsigned int)f2bf(fmaxf(a_[3] + bv_[3], 0.f)) << 16); \
        *(uint2*)&(BOUT)[(m0 + mt_*16 + lr)*ACTP + nW + nt_*16 + lk*4] =      \
            make_uint2(lo_, hi_);                                             \
      }                                                                       \
    }                                                                         \
    __syncthreads();                                                          \
  } while (0)

__global__ __launch_bounds__(512)
__attribute__((amdgpu_waves_per_eu(2, 2)))
void liif_main(
    const float* __restrict__ coord, const float* __restrict__ cell,
    const float* __restrict__ P,  const float* __restrict__ W0,
    const unsigned short* __restrict__ wt,
    const float* __restrict__ b1, const float* __restrict__ b2,
    const float* __restrict__ b3, const float* __restrict__ b4,
    const float* __restrict__ w4t, float* __restrict__ out)
{
  __shared__ __align__(16) unsigned short buf0[NEV*ACTP];  // 67.6 KB
  __shared__ __align__(16) unsigned short buf1[NEV*ACTP];  // 67.6 KB
  __shared__ int   lin_s[NEV];
  __shared__ float r0_s[NEV], r1_s[NEV], rc0_s[NEV], rc1_s[NEV], area_s[NEV];
  float* predp = (float*)buf1;          // overlay (buf1 dead during/after L3)

  const int t   = threadIdx.x;
  const int blk = blockIdx.x;
  const int b   = blk >> 11;            // 2048 blocks per batch
  const int q0  = (blk & 2047) * TQ;

  const int lane = t & 63;
  const int w    = t >> 6;              // 0..7
  const int m0   = (w >> 2) * 64;       // wave row base (0 / 64)
  const int nW   = (w & 3) * 64;        // wave col base (0/64/128/192)
  const int lr   = lane & 15;
  const int lk   = lane >> 4;

  // W register groups; prologue: W1 chunks 0-3 (latency hidden under A/B)
  bf16x8 g0[16], g1[16];
  LOADG(g0, wt, 0);

  // ---- Phase A: indices, rel coords, areas (bit-exact vs numpy fp32) ------
  if (t < NEV) {
    const int e = t;
    const int q = q0 + (e >> 2);
    const int s = e & 3;                // [(-1,-1),(-1,1),(1,-1),(1,1)]
    const size_t cbase = (((size_t)b << 16) + q) * 2;
    float c0 = coord[cbase + 0];
    float c1 = coord[cbase + 1];
    float vx = (s & 2) ? 1.0f : -1.0f;
    float vy = (s & 1) ? 1.0f : -1.0f;
    const float RXY = (float)(1.0/48.0);
    const float CLO = (float)(-1.0 + 1e-6);
    const float CHI = (float)( 1.0 - 1e-6);
    float gx = __fadd_rn(c0, __fadd_rn(__fmul_rn(vx, RXY), 1e-6f));
    float gy = __fadd_rn(c1, __fadd_rn(__fmul_rn(vy, RXY), 1e-6f));
    gx = fminf(fmaxf(gx, CLO), CHI);
    gy = fminf(fmaxf(gy, CLO), CHI);
    float xr = __fmul_rn(__fsub_rn(__fmul_rn(__fadd_rn(gx, 1.0f), 48.0f), 1.0f), 0.5f);
    float xc = __fmul_rn(__fsub_rn(__fmul_rn(__fadd_rn(gy, 1.0f), 48.0f), 1.0f), 0.5f);
    int ir = (int)rintf(xr); ir = ir < 0 ? 0 : (ir > HH-1 ? HH-1 : ir);
    int ic = (int)rintf(xc); ic = ic < 0 ? 0 : (ic > HH-1 ? HH-1 : ic);
    lin_s[e] = ir*HH + ic;
    const float T2 = (float)(2.0/48.0);
    float qcr = __fsub_rn(__fmul_rn(__fadd_rn((float)ir, 0.5f), T2), 1.0f);
    float qcc = __fsub_rn(__fmul_rn(__fadd_rn((float)ic, 0.5f), T2), 1.0f);
    float r0 = __fmul_rn(__fsub_rn(c0, qcr), 48.0f);
    float r1 = __fmul_rn(__fsub_rn(c1, qcc), 48.0f);
    r0_s[e] = r0; r1_s[e] = r1;
    area_s[e] = __fadd_rn(fabsf(__fmul_rn(r0, r1)), 1e-9f);
    rc0_s[e] = __fmul_rn(cell[cbase + 0], 48.0f);
    rc1_s[e] = __fmul_rn(cell[cbase + 1], 48.0f);
  }
  __syncthreads();

  // ---- Phase B: h0 -> bf16 buf0. 512 thr: 128 col-pairs x 4 row-quarters --
  {
    const int c2 = (t & 127) * 2;       // column pair
    const int rq = t >> 7;              // row quarter
    float wA = W0[(size_t)512*HID + c2],  wBv = W0[(size_t)512*HID + c2 + 1];
    float xA = W0[(size_t)513*HID + c2],  xB = W0[(size_t)513*HID + c2 + 1];
    float yA = W0[(size_t)514*HID + c2],  yB = W0[(size_t)514*HID + c2 + 1];
    float zA = W0[(size_t)515*HID + c2],  zB = W0[(size_t)515*HID + c2 + 1];
    const float* Pb = P + (size_t)b * NPOS * HID;
    #pragma unroll 4
    for (int i = 0; i < 32; ++i) {
      const int e = rq*32 + i;
      const float* pr = Pb + (size_t)lin_s[e]*HID + c2;
      float vA = pr[0] + r0_s[e]*wA + r1_s[e]*xA + rc0_s[e]*yA + rc1_s[e]*zA;
      float vB = pr[1] + r0_s[e]*wBv + r1_s[e]*xB + rc0_s[e]*yB + rc1_s[e]*zB;
      unsigned int pk = (unsigned int)f2bf(fmaxf(vA, 0.0f)) |
                        ((unsigned int)f2bf(fmaxf(vB, 0.0f)) << 16);
      *(unsigned int*)&buf0[e*ACTP + c2] = pk;
    }
  }
  __syncthreads();                      // buf0 (h0) ready

  f32x4 acc[16];
  LAYER_MM2(buf0, wt,          wt + 65536,  1);  LAYER_WB2(buf1, b1);  // L1
  LAYER_MM2(buf1, wt + 65536,  wt + 131072, 1);  LAYER_WB2(buf0, b2);  // L2
  LAYER_MM2(buf0, wt + 131072, wt,          0);                        // L3

  // ---- fused final layer: p[mt][o] = sum_n relu(acc+b3) * W4t[o][n] -------
  {
    float p[4][3];
    #pragma unroll
    for (int mt = 0; mt < 4; ++mt)
      { p[mt][0] = 0.f; p[mt][1] = 0.f; p[mt][2] = 0.f; }
    #pragma unroll
    for (int nt = 0; nt < 4; ++nt) {
      f32x4 bv = *(const f32x4*)&b3[nW + nt*16 + lk*4];
      f32x4 w40 = *(const f32x4*)&w4t[      nW + nt*16 + lk*4];
      f32x4 w41 = *(const f32x4*)&w4t[256 + nW + nt*16 + lk*4];
      f32x4 w42 = *(const f32x4*)&w4t[512 + nW + nt*16 + lk*4];
      #pragma unroll
      for (int mt = 0; mt < 4; ++mt) {
        f32x4 a = acc[mt*4 + nt];
        #pragma unroll
        for (int j = 0; j < 4; ++j) {
          float v = fmaxf(a[j] + bv[j], 0.f);
          p[mt][0] += v * w40[j];
          p[mt][1] += v * w41[j];
          p[mt][2] += v * w42[j];
        }
      }
    }
    #pragma unroll
    for (int mt = 0; mt < 4; ++mt)
      #pragma unroll
      for (int o = 0; o < 3; ++o) {
        float s = p[mt][o];
        s += __shfl_xor(s, 16);
        s += __shfl_xor(s, 32);
        p[mt][o] = s;
      }
    if (lk == 0) {                       // lanes 0..15: one writer per m-col
      #pragma unroll
      for (int mt = 0; mt < 4; ++mt) {
        const int m = m0 + mt*16 + lr;
        predp[(w & 3)*384 + m*3 + 0] = p[mt][0];
        predp[(w & 3)*384 + m*3 + 1] = p[mt][1];
        predp[(w & 3)*384 + m*3 + 2] = p[mt][2];
      }
    }
  }
  __syncthreads();

  // ---- blend: pred[e][o] = b4 + sum_wc partials; w[s] = area[3-s]/tot -----
  if (t < TQ*3) {
    const int q = t / 3, o = t - (t/3)*3;
    const int eb = q*4;
    float pe[4];
    #pragma unroll
    for (int s = 0; s < 4; ++s) {
      const int e = eb + s;
      pe[s] = b4[o] + predp[e*3 + o] + predp[384 + e*3 + o]
                    + predp[768 + e*3 + o] + predp[1152 + e*3 + o];
    }
    float a0 = area_s[eb+0], a1 = area_s[eb+1], a2 = area_s[eb+2], a3 = area_s[eb+3];
    float tot = ((a0 + a1) + a2) + a3;
    float rv = (pe[0]*a3 + pe[1]*a2 + pe[2]*a1 + pe[3]*a0) / tot;
    out[(((size_t)b << 16) + (q0 + q))*3 + o] = rv;
  }
}

// ---------------------------------------------------------------------------
extern "C" void kernel_launch(void* const* d_in, const int* in_sizes, int n_in,
                              void* d_out, int out_size, void* d_ws, size_t ws_size,
                              hipStream_t stream)
{
  const float* feat  = (const float*)d_in[0];
  const float* coord = (const float*)d_in[1];
  const float* cell  = (const float*)d_in[2];
  const float* W0    = (const float*)d_in[3];
  const float* b0    = (const float*)d_in[4];
  const float* W1    = (const float*)d_in[5];
  const float* b1    = (const float*)d_in[6];
  const float* W2    = (const float*)d_in[7];
  const float* b2    = (const float*)d_in[8];
  const float* W3    = (const float*)d_in[9];
  const float* b3    = (const float*)d_in[10];
  const float* W4    = (const float*)d_in[11];
  const float* b4    = (const float*)d_in[12];
  float* outp = (float*)d_out;

  // ws layout: P f32 [2*2304*256] = 4,718,592 B | Wt bf16 3*64K = 393,216 B
  //            | W4t f32 3*256 = 3,072 B
  float*          P    = (float*)d_ws;
  unsigned short* wtp  = (unsigned short*)((char*)d_ws + 4718592);
  float*          w4tp = (float*)((char*)d_ws + 4718592 + 393216);

  hipLaunchKernelGGL(liif_precompute, dim3(2*(NPOS/4)), dim3(256), 0, stream,
                     feat, W0, b0, P);
  hipLaunchKernelGGL(liif_convert, dim3(769), dim3(256), 0, stream,
                     W1, W2, W3, W4, wtp, w4tp);
  hipLaunchKernelGGL(liif_main, dim3(4096), dim3(512), 0, stream,
                     coord, cell, P, W0, wtp, b1, b2, b3, b4, w4tp, outp);
}

// Round 9
// 403.127 us; speedup vs baseline: 1.4374x; 1.3052x over previous
//
#include <hip/hip_runtime.h>
#include <math.h>

#define HH    48
#define CFEAT 512
#define HID   256
#define NPOS  (HH*HH)   // 2304
#define TQ    64        // queries per block
#define NEV   256       // evals per block = TQ*4

typedef __attribute__((ext_vector_type(8))) short bf16x8;
typedef __attribute__((ext_vector_type(4))) float f32x4;

static __device__ __forceinline__ unsigned short f2bf(float x) {
  unsigned int u = __float_as_uint(x);
  u += 0x7fffu + ((u >> 16) & 1u);     // RNE
  return (unsigned short)(u >> 16);
}

// index/rel math shared (bit-exact) by Phase A and blend-area recompute
static __device__ __forceinline__ void rel_calc(float c0, float c1, int s,
                                                float& r0, float& r1,
                                                int& ir, int& ic) {
  float vx = (s & 2) ? 1.0f : -1.0f;
  float vy = (s & 1) ? 1.0f : -1.0f;
  const float RXY = (float)(1.0/48.0);
  const float CLO = (float)(-1.0 + 1e-6);
  const float CHI = (float)( 1.0 - 1e-6);
  float gx = __fadd_rn(c0, __fadd_rn(__fmul_rn(vx, RXY), 1e-6f));
  float gy = __fadd_rn(c1, __fadd_rn(__fmul_rn(vy, RXY), 1e-6f));
  gx = fminf(fmaxf(gx, CLO), CHI);
  gy = fminf(fmaxf(gy, CLO), CHI);
  float xr = __fmul_rn(__fsub_rn(__fmul_rn(__fadd_rn(gx, 1.0f), 48.0f), 1.0f), 0.5f);
  float xc = __fmul_rn(__fsub_rn(__fmul_rn(__fadd_rn(gy, 1.0f), 48.0f), 1.0f), 0.5f);
  ir = (int)rintf(xr); ir = ir < 0 ? 0 : (ir > HH-1 ? HH-1 : ir);
  ic = (int)rintf(xc); ic = ic < 0 ? 0 : (ic > HH-1 ? HH-1 : ic);
  const float T2 = (float)(2.0/48.0);
  float qcr = __fsub_rn(__fmul_rn(__fadd_rn((float)ir, 0.5f), T2), 1.0f);
  float qcc = __fsub_rn(__fmul_rn(__fadd_rn((float)ic, 0.5f), T2), 1.0f);
  r0 = __fmul_rn(__fsub_rn(c0, qcr), 48.0f);
  r1 = __fmul_rn(__fsub_rn(c1, qcc), 48.0f);
}

// ---------------------------------------------------------------------------
// Kernel 1: P[b][pos][n] = b0[n] + sum_c feat[b][c][pos] * W0[c][n]  (fp32)
// ---------------------------------------------------------------------------
__global__ __launch_bounds__(256) void liif_precompute(
    const float* __restrict__ feat, const float* __restrict__ W0,
    const float* __restrict__ b0, float* __restrict__ P)
{
  int blk = blockIdx.x;                 // 0..1151
  int b   = blk / (NPOS/4);
  int p0  = (blk - b*(NPOS/4)) * 4;
  int n   = threadIdx.x;
  const float* f = feat + (size_t)b * CFEAT * NPOS + p0;
  float bias = b0[n];
  float a0 = bias, a1 = bias, a2 = bias, a3 = bias;
  #pragma unroll 4
  for (int c = 0; c < CFEAT; ++c) {
    float w = W0[c*HID + n];
    const float* fr = f + (size_t)c * NPOS;
    a0 += fr[0]*w; a1 += fr[1]*w; a2 += fr[2]*w; a3 += fr[3]*w;
  }
  float* Pp = P + ((size_t)b*NPOS + p0)*HID + n;
  Pp[0*HID] = a0; Pp[1*HID] = a1; Pp[2*HID] = a2; Pp[3*HID] = a3;
}

// ---------------------------------------------------------------------------
// Kernel 2: transpose+convert W1..W3 -> bf16 Wt[l][n][k]; W4 -> f32 W4t[o][k]
// ---------------------------------------------------------------------------
__global__ __launch_bounds__(256) void liif_convert(
    const float* __restrict__ W1, const float* __restrict__ W2,
    const float* __restrict__ W3, const float* __restrict__ W4,
    unsigned short* __restrict__ wt, float* __restrict__ w4t)
{
  int b = blockIdx.x, t = threadIdx.x;
  if (b < 768) {
    int l = b >> 8, n = b & 255;
    const float* W = (l == 0) ? W1 : (l == 1) ? W2 : W3;
    wt[l*65536 + n*256 + t] = f2bf(W[t*256 + n]);   // Wt[n][k] = W[k][n]
  } else {
    for (int o = 0; o < 3; ++o) w4t[o*256 + t] = W4[t*3 + o];
  }
}

// ---------------------------------------------------------------------------
// Kernel 3: fused main. 256 evals/block, 1024 thr / 16 waves (grid 4x4),
// wave tile 64x64 (acc 64 regs -> AGPR; arch<=64 => 4 waves/SIMD, proven r6).
// act: XOR-swizzled unpadded [256 rows][512 B] (131 KB).
// W: L2 -> reg -> LDS (T14 split), double-buffered 16 KB K=32 chunks,
// one barrier per kstep (T3 2-phase). LDS = exactly 160 KiB.
// ---------------------------------------------------------------------------
// LDS map:
//   [0, 131072)        act (swizzled). After L3: predp overlay (12 KB).
//   [131072, 147456)   wbuf0
//   [147456, 163840)   wbuf1; first 5 KB = {lin_s,r0,r1,rc0,rc1} in Phase A/B.
//
// act swizzle: byte(row, colByte) = row*512 + (colByte ^ ((row&7)<<4))
//   -> b128 reads by 16 lr-lanes hit 8 bank groups (2-way, free).
// wbuf swizzle: byte(n, kgrp) = n*64 + ((kgrp ^ (n&3))<<4) -> 2-way.

#define LDSA   0
#define LDSW   131072
#define LDSM   147456

#define MF(A, B, C) __builtin_amdgcn_mfma_f32_16x16x32_bf16((A), (B), (C), 0, 0, 0)

// one K=32 step: optional stage-load of next chunk, 4 W + 4 act reads,
// 16 MFMA, optional stage-write, barrier.
#define KSTEP(KC, HASN, NLOFF, NKC) do {                                      \
    if (HASN) sreg = *(const f32x4*)(wtb + (NLOFF) + (NKC)*64 + stoff);       \
    const unsigned char* wb_ = lds + LDSW + (((KC)&1)*16384) + lwoff;         \
    bf16x8 w0_ = *(const bf16x8*)(wb_ + 0);                                   \
    bf16x8 w1_ = *(const bf16x8*)(wb_ + 1024);                                \
    bf16x8 w2_ = *(const bf16x8*)(wb_ + 2048);                                \
    bf16x8 w3_ = *(const bf16x8*)(wb_ + 3072);                                \
    const int ko_ = (((KC) << 6) ^ xb6);                                      \
    bf16x8 a0_ = *(const bf16x8*)(lds + rb0 + ko_);                           \
    bf16x8 a1_ = *(const bf16x8*)(lds + rb1 + ko_);                           \
    bf16x8 a2_ = *(const bf16x8*)(lds + rb2 + ko_);                           \
    bf16x8 a3_ = *(const bf16x8*)(lds + rb3 + ko_);                           \
    acc[0]  = MF(w0_, a0_, acc[0]);  acc[1]  = MF(w1_, a0_, acc[1]);          \
    acc[2]  = MF(w2_, a0_, acc[2]);  acc[3]  = MF(w3_, a0_, acc[3]);          \
    acc[4]  = MF(w0_, a1_, acc[4]);  acc[5]  = MF(w1_, a1_, acc[5]);          \
    acc[6]  = MF(w2_, a1_, acc[6]);  acc[7]  = MF(w3_, a1_, acc[7]);          \
    acc[8]  = MF(w0_, a2_, acc[8]);  acc[9]  = MF(w1_, a2_, acc[9]);          \
    acc[10] = MF(w2_, a2_, acc[10]); acc[11] = MF(w3_, a2_, acc[11]);         \
    acc[12] = MF(w0_, a3_, acc[12]); acc[13] = MF(w1_, a3_, acc[13]);         \
    acc[14] = MF(w2_, a3_, acc[14]); acc[15] = MF(w3_, a3_, acc[15]);         \
    if (HASN) *(f32x4*)(lds + LDSW + ((((KC)+1)&1)*16384) + sdst) = sreg;     \
    __syncthreads();                                                          \
  } while (0)

// full layer: entering, wbuf[0] holds this layer's chunk0.
#define LAYER3(LOFF, NLOFF, LAST) do {                                        \
    _Pragma("unroll")                                                         \
    for (int i_ = 0; i_ < 16; ++i_) acc[i_] = (f32x4){0.f, 0.f, 0.f, 0.f};    \
    KSTEP(0, 1, (LOFF), 1); KSTEP(1, 1, (LOFF), 2);                           \
    KSTEP(2, 1, (LOFF), 3); KSTEP(3, 1, (LOFF), 4);                           \
    KSTEP(4, 1, (LOFF), 5); KSTEP(5, 1, (LOFF), 6);                           \
    KSTEP(6, 1, (LOFF), 7); KSTEP(7, !(LAST), (NLOFF), 0);                    \
  } while (0)

// bias+relu -> bf16 writeback into swizzled act, then barrier
#define LAYER_WB3(BIAS) do {                                                  \
    _Pragma("unroll")                                                         \
    for (int nt_ = 0; nt_ < 4; ++nt_) {                                       \
      f32x4 bv_ = *(const f32x4*)&(BIAS)[nW + nt_*16 + lk*4];                 \
      const int cb_ = (cwb + nt_*32) ^ xwb;                                   \
      _Pragma("unroll")                                                       \
      for (int mt_ = 0; mt_ < 4; ++mt_) {                                     \
        f32x4 a_ = acc[mt_*4 + nt_];                                          \
        unsigned int lo_ = (unsigned int)f2bf(fmaxf(a_[0] + bv_[0], 0.f))     \
                         | ((unsigned int)f2bf(fmaxf(a_[1] + bv_[1], 0.f)) << 16); \
        unsigned int hi_ = (unsigned int)f2bf(fmaxf(a_[2] + bv_[2], 0.f))     \
                         | ((unsigned int)f2bf(fmaxf(a_[3] + bv_[3], 0.f)) << 16); \
        *(uint2*)(lds + ((m0 + mt_*16 + lr) << 9) + cb_) = make_uint2(lo_, hi_); \
      }                                                                       \
    }                                                                         \
    __syncthreads();                                                          \
  } while (0)

__global__ __launch_bounds__(1024, 4)
__attribute__((amdgpu_waves_per_eu(4, 4)))
void liif_main(
    const float* __restrict__ coord, const float* __restrict__ cell,
    const float* __restrict__ P,  const float* __restrict__ W0,
    const unsigned short* __restrict__ wt,
    const float* __restrict__ b1, const float* __restrict__ b2,
    const float* __restrict__ b3, const float* __restrict__ b4,
    const float* __restrict__ w4t, float* __restrict__ out)
{
  __shared__ __align__(16) unsigned char lds[163840];
  int*   lin_s = (int*)  (lds + LDSM);
  float* r0_s  = (float*)(lds + LDSM + 1024);
  float* r1_s  = (float*)(lds + LDSM + 2048);
  float* rc0_s = (float*)(lds + LDSM + 3072);
  float* rc1_s = (float*)(lds + LDSM + 4096);
  float* predp = (float*)lds;           // [4 wc][256 m][3 o] = 12 KB overlay

  const int t   = threadIdx.x;
  const int blk = blockIdx.x;
  const int b   = blk >> 10;            // 1024 blocks per batch
  const int q0  = (blk & 1023) * TQ;

  const int lane = t & 63;
  const int w    = t >> 6;              // 0..15
  const int m0   = (w >> 2) * 64;       // wave row base
  const int wc   = w & 3;
  const int nW   = wc * 64;             // wave col base
  const int lr   = lane & 15;
  const int lk   = lane >> 4;

  // staging (per-thread constants)
  const int sn    = t >> 2, ssub = t & 3;
  const int stoff = sn*512 + ssub*16;                   // global byte off in layer
  const int sdst  = sn*64 + ((ssub ^ (sn & 3)) << 4);   // swizzled LDS chunk off
  const char* wtb = (const char*)wt;
  f32x4 sreg;

  // W-read base: + nt*1024 + (kc&1)*16384
  const int lwoff = nW*64 + lr*64 + ((lk ^ (lr & 3)) << 4);
  // act-read bases (swizzle split: low XOR into lk*16, kc-bit XOR via xb6)
  const int xl  = (lr & 3) << 4;
  const int xb6 = ((lr >> 2) & 1) << 6;
  const int rb0 = ((m0 +  0 + lr) << 9) + ((lk << 4) ^ xl);
  const int rb1 = ((m0 + 16 + lr) << 9) + ((lk << 4) ^ xl);
  const int rb2 = ((m0 + 32 + lr) << 9) + ((lk << 4) ^ xl);
  const int rb3 = ((m0 + 48 + lr) << 9) + ((lk << 4) ^ xl);
  // writeback constants
  const int cwb = wc*128 + lk*8;
  const int xwb = (lr & 7) << 4;

  // ---- Phase A: indices + rel coords into misc (wbuf1 region) -------------
  if (t < NEV) {
    const int e = t;
    const int q = q0 + (e >> 2);
    const int s = e & 3;                // [(-1,-1),(-1,1),(1,-1),(1,1)]
    const size_t cbase = (((size_t)b << 16) + q) * 2;
    float c0 = coord[cbase + 0];
    float c1 = coord[cbase + 1];
    float r0, r1; int ir, ic;
    rel_calc(c0, c1, s, r0, r1, ir, ic);
    lin_s[e] = ir*HH + ic;
    r0_s[e] = r0; r1_s[e] = r1;
    rc0_s[e] = __fmul_rn(cell[cbase + 0], 48.0f);
    rc1_s[e] = __fmul_rn(cell[cbase + 1], 48.0f);
  }
  __syncthreads();

  // issue L1 chunk0 stage-load early (lands during Phase B)
  sreg = *(const f32x4*)(wtb + 0 + stoff);

  // ---- Phase B: h0 -> swizzled act. 1024 thr: 128 col-pairs x 8 row-octs --
  {
    const int c2 = (t & 127) * 2;
    const int rq = t >> 7;              // 0..7
    float wA = W0[(size_t)512*HID + c2],  wBv = W0[(size_t)512*HID + c2 + 1];
    float xA = W0[(size_t)513*HID + c2],  xB = W0[(size_t)513*HID + c2 + 1];
    float yA = W0[(size_t)514*HID + c2],  yB = W0[(size_t)514*HID + c2 + 1];
    float zA = W0[(size_t)515*HID + c2],  zB = W0[(size_t)515*HID + c2 + 1];
    const float* Pb = P + (size_t)b * NPOS * HID;
    #pragma unroll 4
    for (int i = 0; i < 32; ++i) {
      const int e = rq*32 + i;
      const float* pr = Pb + (size_t)lin_s[e]*HID + c2;
      float vA = pr[0] + r0_s[e]*wA + r1_s[e]*xA + rc0_s[e]*yA + rc1_s[e]*zA;
      float vB = pr[1] + r0_s[e]*wBv + r1_s[e]*xB + rc0_s[e]*yB + rc1_s[e]*zB;
      unsigned int pk = (unsigned int)f2bf(fmaxf(vA, 0.0f)) |
                        ((unsigned int)f2bf(fmaxf(vB, 0.0f)) << 16);
      *(unsigned int*)(lds + (e << 9) + ((c2*2) ^ ((e & 7) << 4))) = pk;
    }
  }
  // write staged L1c0 into wbuf0 (disjoint from misc/act), then barrier
  *(f32x4*)(lds + LDSW + sdst) = sreg;
  __syncthreads();

  // ---- Layers 1..3 ---------------------------------------------------------
  f32x4 acc[16];
  LAYER3(0,      65536*2, 0);  LAYER_WB3(b1);   // L1 (stages L2c0 at kc7)
  LAYER3(65536*2, 65536*4, 0); LAYER_WB3(b2);   // L2 (stages L3c0 at kc7)
  LAYER3(65536*4, 0, 1);                        // L3 (no next)

  // ---- fused final layer: p[mt][o] = sum_n relu(acc+b3) * W4t[o][n] -------
  {
    float p[4][3];
    #pragma unroll
    for (int mt = 0; mt < 4; ++mt)
      { p[mt][0] = 0.f; p[mt][1] = 0.f; p[mt][2] = 0.f; }
    #pragma unroll
    for (int nt = 0; nt < 4; ++nt) {
      f32x4 bv  = *(const f32x4*)&b3[nW + nt*16 + lk*4];
      f32x4 w40 = *(const f32x4*)&w4t[      nW + nt*16 + lk*4];
      f32x4 w41 = *(const f32x4*)&w4t[256 + nW + nt*16 + lk*4];
      f32x4 w42 = *(const f32x4*)&w4t[512 + nW + nt*16 + lk*4];
      #pragma unroll
      for (int mt = 0; mt < 4; ++mt) {
        f32x4 a = acc[mt*4 + nt];
        #pragma unroll
        for (int j = 0; j < 4; ++j) {
          float v = fmaxf(a[j] + bv[j], 0.f);
          p[mt][0] += v * w40[j];
          p[mt][1] += v * w41[j];
          p[mt][2] += v * w42[j];
        }
      }
    }
    #pragma unroll
    for (int mt = 0; mt < 4; ++mt)
      #pragma unroll
      for (int o = 0; o < 3; ++o) {
        float s = p[mt][o];
        s += __shfl_xor(s, 16);
        s += __shfl_xor(s, 32);
        p[mt][o] = s;
      }
    if (lk == 0) {                       // lanes 0..15: one writer per m-col
      #pragma unroll
      for (int mt = 0; mt < 4; ++mt) {
        const int m = m0 + mt*16 + lr;
        predp[wc*768 + m*3 + 0] = p[mt][0];
        predp[wc*768 + m*3 + 1] = p[mt][1];
        predp[wc*768 + m*3 + 2] = p[mt][2];
      }
    }
  }
  __syncthreads();

  // ---- blend: pred[e][o] = b4 + sum_wc partials; w[s] = area[3-s]/tot -----
  if (t < TQ*3) {
    const int q = t / 3, o = t - (t/3)*3;
    const int eb = q*4;
    const size_t cbase = (((size_t)b << 16) + (q0 + q)) * 2;
    float c0 = coord[cbase + 0];
    float c1 = coord[cbase + 1];
    float ar[4];
    #pragma unroll
    for (int s = 0; s < 4; ++s) {
      float r0, r1; int ir, ic;
      rel_calc(c0, c1, s, r0, r1, ir, ic);
      ar[s] = __fadd_rn(fabsf(__fmul_rn(r0, r1)), 1e-9f);
    }
    float pe[4];
    #pragma unroll
    for (int s = 0; s < 4; ++s) {
      const int e = eb + s;
      pe[s] = b4[o] + predp[e*3 + o] + predp[768 + e*3 + o]
                    + predp[1536 + e*3 + o] + predp[2304 + e*3 + o];
    }
    float tot = ((ar[0] + ar[1]) + ar[2]) + ar[3];
    float rv = (pe[0]*ar[3] + pe[1]*ar[2] + pe[2]*ar[1] + pe[3]*ar[0]) / tot;
    out[(((size_t)b << 16) + (q0 + q))*3 + o] = rv;
  }
}

// ---------------------------------------------------------------------------
extern "C" void kernel_launch(void* const* d_in, const int* in_sizes, int n_in,
                              void* d_out, int out_size, void* d_ws, size_t ws_size,
                              hipStream_t stream)
{
  const float* feat  = (const float*)d_in[0];
  const float* coord = (const float*)d_in[1];
  const float* cell  = (const float*)d_in[2];
  const float* W0    = (const float*)d_in[3];
  const float* b0    = (const float*)d_in[4];
  const float* W1    = (const float*)d_in[5];
  const float* b1    = (const float*)d_in[6];
  const float* W2    = (const float*)d_in[7];
  const float* b2    = (const float*)d_in[8];
  const float* W3    = (const float*)d_in[9];
  const float* b3    = (const float*)d_in[10];
  const float* W4    = (const float*)d_in[11];
  const float* b4    = (const float*)d_in[12];
  float* outp = (float*)d_out;

  // ws layout: P f32 [2*2304*256] = 4,718,592 B | Wt bf16 3*64K = 393,216 B
  //            | W4t f32 3*256 = 3,072 B
  float*          P    = (float*)d_ws;
  unsigned short* wtp  = (unsigned short*)((char*)d_ws + 4718592);
  float*          w4tp = (float*)((char*)d_ws + 4718592 + 393216);

  hipLaunchKernelGGL(liif_precompute, dim3(2*(NPOS/4)), dim3(256), 0, stream,
                     feat, W0, b0, P);
  hipLaunchKernelGGL(liif_convert, dim3(769), dim3(256), 0, stream,
                     W1, W2, W3, W4, wtp, w4tp);
  hipLaunchKernelGGL(liif_main, dim3(2048), dim3(1024), 0, stream,
                     coord, cell, P, W0, wtp, b1, b2, b3, b4, w4tp, outp);
}

// Round 10
// 320.837 us; speedup vs baseline: 1.8061x; 1.2565x over previous
//
#include <hip/hip_runtime.h>
#include <math.h>

#define HH    48
#define CFEAT 512
#define HID   256
#define NPOS  (HH*HH)   // 2304
#define TQ    64        // queries per block
#define NEV   256       // evals per block = TQ*4

typedef __attribute__((ext_vector_type(8))) short bf16x8;
typedef __attribute__((ext_vector_type(4))) float f32x4;

static __device__ __forceinline__ unsigned short f2bf(float x) {
  unsigned int u = __float_as_uint(x);
  u += 0x7fffu + ((u >> 16) & 1u);     // RNE
  return (unsigned short)(u >> 16);
}

// index/rel math shared (bit-exact) by Phase A and blend-area recompute
static __device__ __forceinline__ void rel_calc(float c0, float c1, int s,
                                                float& r0, float& r1,
                                                int& ir, int& ic) {
  float vx = (s & 2) ? 1.0f : -1.0f;
  float vy = (s & 1) ? 1.0f : -1.0f;
  const float RXY = (float)(1.0/48.0);
  const float CLO = (float)(-1.0 + 1e-6);
  const float CHI = (float)( 1.0 - 1e-6);
  float gx = __fadd_rn(c0, __fadd_rn(__fmul_rn(vx, RXY), 1e-6f));
  float gy = __fadd_rn(c1, __fadd_rn(__fmul_rn(vy, RXY), 1e-6f));
  gx = fminf(fmaxf(gx, CLO), CHI);
  gy = fminf(fmaxf(gy, CLO), CHI);
  float xr = __fmul_rn(__fsub_rn(__fmul_rn(__fadd_rn(gx, 1.0f), 48.0f), 1.0f), 0.5f);
  float xc = __fmul_rn(__fsub_rn(__fmul_rn(__fadd_rn(gy, 1.0f), 48.0f), 1.0f), 0.5f);
  ir = (int)rintf(xr); ir = ir < 0 ? 0 : (ir > HH-1 ? HH-1 : ir);
  ic = (int)rintf(xc); ic = ic < 0 ? 0 : (ic > HH-1 ? HH-1 : ic);
  const float T2 = (float)(2.0/48.0);
  float qcr = __fsub_rn(__fmul_rn(__fadd_rn((float)ir, 0.5f), T2), 1.0f);
  float qcc = __fsub_rn(__fmul_rn(__fadd_rn((float)ic, 0.5f), T2), 1.0f);
  r0 = __fmul_rn(__fsub_rn(c0, qcr), 48.0f);
  r1 = __fmul_rn(__fsub_rn(c1, qcc), 48.0f);
}

// ---------------------------------------------------------------------------
// Kernel 1: P[b][pos][n] = b0[n] + sum_c feat[b][c][pos] * W0[c][n]  (fp32)
// ---------------------------------------------------------------------------
__global__ __launch_bounds__(256) void liif_precompute(
    const float* __restrict__ feat, const float* __restrict__ W0,
    const float* __restrict__ b0, float* __restrict__ P)
{
  int blk = blockIdx.x;                 // 0..1151
  int b   = blk / (NPOS/4);
  int p0  = (blk - b*(NPOS/4)) * 4;
  int n   = threadIdx.x;
  const float* f = feat + (size_t)b * CFEAT * NPOS + p0;
  float bias = b0[n];
  float a0 = bias, a1 = bias, a2 = bias, a3 = bias;
  #pragma unroll 4
  for (int c = 0; c < CFEAT; ++c) {
    float w = W0[c*HID + n];
    const float* fr = f + (size_t)c * NPOS;
    a0 += fr[0]*w; a1 += fr[1]*w; a2 += fr[2]*w; a3 += fr[3]*w;
  }
  float* Pp = P + ((size_t)b*NPOS + p0)*HID + n;
  Pp[0*HID] = a0; Pp[1*HID] = a1; Pp[2*HID] = a2; Pp[3*HID] = a3;
}

// ---------------------------------------------------------------------------
// Kernel 2: build pre-permuted W image for linear global_load_lds staging.
// Image chunk (l,kc) is 16 KB; 16-B unit p (0..1023):
//   wc = p>>8, i = p&255, n = wc*64 + (i>>2), lk = i&3
//   unit holds Wt[n][kc*32 + lk*8 .. +8]  (Wt[n][k] = W[k][n], bf16)
// => a W-frag read (wave wc, frag nt) covers 1024 consecutive LDS bytes.
// Also W4 -> f32 W4t[o][k].
// ---------------------------------------------------------------------------
__global__ __launch_bounds__(256) void liif_convert(
    const float* __restrict__ W1, const float* __restrict__ W2,
    const float* __restrict__ W3, const float* __restrict__ W4,
    unsigned char* __restrict__ img, float* __restrict__ w4t)
{
  int blk = blockIdx.x, t = threadIdx.x;
  if (blk < 24) {
    int l = blk >> 3, kc = blk & 7;
    const float* W = (l == 0) ? W1 : (l == 1) ? W2 : W3;
    unsigned short* dst = (unsigned short*)(img + (size_t)blk * 16384);
    #pragma unroll 1
    for (int s = 0; s < 4; ++s) {
      int p  = t + s*256;
      int wc = p >> 8, i = p & 255;
      int n  = wc*64 + (i >> 2);
      int lk = i & 3;
      #pragma unroll
      for (int j = 0; j < 8; ++j) {
        int k = kc*32 + lk*8 + j;
        dst[p*8 + j] = f2bf(W[k*256 + n]);
      }
    }
  } else {
    for (int o = 0; o < 3; ++o) w4t[o*256 + t] = W4[t*3 + o];
  }
}

// ---------------------------------------------------------------------------
// Kernel 3: fused main. 256 evals/block, 1024 thr / 16 waves (grid 4x4),
// wave tile 64x64. act: XOR-swizzled [256 rows][512 B] (131 KB).
// W: global_load_lds DMA (zero staging VGPRs), double-buffered 16 KB chunks,
// pre-permuted image -> conflict-free W reads. One barrier per kstep.
// ---------------------------------------------------------------------------
// LDS map:
//   [0, 131072)        act (swizzled). After L3: predp overlay (12 KB).
//   [131072, 147456)   wbuf0
//   [147456, 163840)   wbuf1; first 5 KB = {lin_s,r0,r1,rc0,rc1} in Phase A/B.

#define LDSA   0
#define LDSW   131072
#define LDSM   147456

#define MF(A, B, C) __builtin_amdgcn_mfma_f32_16x16x32_bf16((A), (B), (C), 0, 0, 0)

#define AS1(p) ((const __attribute__((address_space(1))) void*)(unsigned long long)(const void*)(p))
#define AS3(p) ((__attribute__((address_space(3))) void*)(unsigned int)(unsigned long long)(void*)(p))

// DMA one 16 KB chunk: each thread 16 B; wave w covers [w*1024, +1024)
#define STAGE(LOFF, NKC, BUF) \
  __builtin_amdgcn_global_load_lds( \
      AS1(img + (LOFF) + (NKC)*16384 + sgoff), \
      AS3(lds + LDSW + (BUF)*16384 + swoff), 16, 0, 0)

// one K=32 step: optional DMA of next chunk, 4 W + 4 act reads, 16 MFMA,
// barrier (compiler-emitted vmcnt(0) drains the DMA before s_barrier).
#define KSTEP(KC, HASN, NLOFF, NKC) do {                                      \
    if (HASN) STAGE(NLOFF, NKC, (((KC)+1)&1));                                \
    const unsigned char* wb_ = lds + LDSW + (((KC)&1)*16384) + lwoff;         \
    bf16x8 w0_ = *(const bf16x8*)(wb_ + 0);                                   \
    bf16x8 w1_ = *(const bf16x8*)(wb_ + 1024);                                \
    bf16x8 w2_ = *(const bf16x8*)(wb_ + 2048);                                \
    bf16x8 w3_ = *(const bf16x8*)(wb_ + 3072);                                \
    const int ko_ = (((KC) << 6) ^ xb6);                                      \
    bf16x8 a0_ = *(const bf16x8*)(lds + rb0 + ko_);                           \
    bf16x8 a1_ = *(const bf16x8*)(lds + rb1 + ko_);                           \
    bf16x8 a2_ = *(const bf16x8*)(lds + rb2 + ko_);                           \
    bf16x8 a3_ = *(const bf16x8*)(lds + rb3 + ko_);                           \
    acc[0]  = MF(w0_, a0_, acc[0]);  acc[1]  = MF(w1_, a0_, acc[1]);          \
    acc[2]  = MF(w2_, a0_, acc[2]);  acc[3]  = MF(w3_, a0_, acc[3]);          \
    acc[4]  = MF(w0_, a1_, acc[4]);  acc[5]  = MF(w1_, a1_, acc[5]);          \
    acc[6]  = MF(w2_, a1_, acc[6]);  acc[7]  = MF(w3_, a1_, acc[7]);          \
    acc[8]  = MF(w0_, a2_, acc[8]);  acc[9]  = MF(w1_, a2_, acc[9]);          \
    acc[10] = MF(w2_, a2_, acc[10]); acc[11] = MF(w3_, a2_, acc[11]);         \
    acc[12] = MF(w0_, a3_, acc[12]); acc[13] = MF(w1_, a3_, acc[13]);         \
    acc[14] = MF(w2_, a3_, acc[14]); acc[15] = MF(w3_, a3_, acc[15]);         \
    __syncthreads();                                                          \
  } while (0)

// full layer: entering, wbuf[0] holds this layer's chunk0.
#define LAYER3(LOFF, NLOFF, LAST) do {                                        \
    _Pragma("unroll")                                                         \
    for (int i_ = 0; i_ < 16; ++i_) acc[i_] = (f32x4){0.f, 0.f, 0.f, 0.f};    \
    KSTEP(0, 1, (LOFF), 1); KSTEP(1, 1, (LOFF), 2);                           \
    KSTEP(2, 1, (LOFF), 3); KSTEP(3, 1, (LOFF), 4);                           \
    KSTEP(4, 1, (LOFF), 5); KSTEP(5, 1, (LOFF), 6);                           \
    KSTEP(6, 1, (LOFF), 7); KSTEP(7, !(LAST), (NLOFF), 0);                    \
  } while (0)

// bias+relu -> bf16 writeback into swizzled act, then barrier
#define LAYER_WB3(BIAS) do {                                                  \
    _Pragma("unroll")                                                         \
    for (int nt_ = 0; nt_ < 4; ++nt_) {                                       \
      f32x4 bv_ = *(const f32x4*)&(BIAS)[nW + nt_*16 + lk*4];                 \
      const int cb_ = (cwb + nt_*32) ^ xwb;                                   \
      _Pragma("unroll")                                                       \
      for (int mt_ = 0; mt_ < 4; ++mt_) {                                     \
        f32x4 a_ = acc[mt_*4 + nt_];                                          \
        unsigned int lo_ = (unsigned int)f2bf(fmaxf(a_[0] + bv_[0], 0.f))     \
                         | ((unsigned int)f2bf(fmaxf(a_[1] + bv_[1], 0.f)) << 16); \
        unsigned int hi_ = (unsigned int)f2bf(fmaxf(a_[2] + bv_[2], 0.f))     \
                         | ((unsigned int)f2bf(fmaxf(a_[3] + bv_[3], 0.f)) << 16); \
        *(uint2*)(lds + ((m0 + mt_*16 + lr) << 9) + cb_) = make_uint2(lo_, hi_); \
      }                                                                       \
    }                                                                         \
    __syncthreads();                                                          \
  } while (0)

__global__ __launch_bounds__(1024, 4)
__attribute__((amdgpu_waves_per_eu(4, 4)))
void liif_main(
    const float* __restrict__ coord, const float* __restrict__ cell,
    const float* __restrict__ P,  const float* __restrict__ W0,
    const unsigned char* __restrict__ img,
    const float* __restrict__ b1, const float* __restrict__ b2,
    const float* __restrict__ b3, const float* __restrict__ b4,
    const float* __restrict__ w4t, float* __restrict__ out)
{
  __shared__ __align__(16) unsigned char lds[163840];
  int*   lin_s = (int*)  (lds + LDSM);
  float* r0_s  = (float*)(lds + LDSM + 1024);
  float* r1_s  = (float*)(lds + LDSM + 2048);
  float* rc0_s = (float*)(lds + LDSM + 3072);
  float* rc1_s = (float*)(lds + LDSM + 4096);
  float* predp = (float*)lds;           // [4 wc][256 m][3 o] = 12 KB overlay

  const int t   = threadIdx.x;
  const int blk = blockIdx.x;
  const int b   = blk >> 10;            // 1024 blocks per batch
  const int q0  = (blk & 1023) * TQ;

  const int lane = t & 63;
  const int w    = t >> 6;              // 0..15
  const int m0   = (w >> 2) * 64;       // wave row base
  const int wc   = w & 3;
  const int nW   = wc * 64;             // wave col base
  const int lr   = lane & 15;
  const int lk   = lane >> 4;

  // DMA staging offsets
  const size_t sgoff = (size_t)t * 16;  // per-lane global offset in chunk
  const int    swoff = w * 1024;        // wave-uniform LDS slice base

  // W-read base: conflict-free image layout
  const int lwoff = wc*4096 + lr*64 + lk*16;   // + nt*1024
  // act-read bases (swizzle: colbyte ^ ((row&7)<<4), split into xl | xb6)
  const int xl  = (lr & 3) << 4;
  const int xb6 = ((lr >> 2) & 1) << 6;
  const int rb0 = ((m0 +  0 + lr) << 9) + ((lk << 4) ^ xl);
  const int rb1 = ((m0 + 16 + lr) << 9) + ((lk << 4) ^ xl);
  const int rb2 = ((m0 + 32 + lr) << 9) + ((lk << 4) ^ xl);
  const int rb3 = ((m0 + 48 + lr) << 9) + ((lk << 4) ^ xl);
  // writeback constants
  const int cwb = wc*128 + lk*8;
  const int xwb = (lr & 7) << 4;

  // ---- Phase A: indices + rel coords into misc (wbuf1 region) -------------
  if (t < NEV) {
    const int e = t;
    const int q = q0 + (e >> 2);
    const int s = e & 3;                // [(-1,-1),(-1,1),(1,-1),(1,1)]
    const size_t cbase = (((size_t)b << 16) + q) * 2;
    float c0 = coord[cbase + 0];
    float c1 = coord[cbase + 1];
    float r0, r1; int ir, ic;
    rel_calc(c0, c1, s, r0, r1, ir, ic);
    lin_s[e] = ir*HH + ic;
    r0_s[e] = r0; r1_s[e] = r1;
    rc0_s[e] = __fmul_rn(cell[cbase + 0], 48.0f);
    rc1_s[e] = __fmul_rn(cell[cbase + 1], 48.0f);
  }
  __syncthreads();

  // issue L1 chunk0 DMA early (drained by Phase B's ending barrier)
  STAGE(0, 0, 0);

  // ---- Phase B: h0 -> swizzled act. 1024 thr: 128 col-pairs x 8 row-octs --
  {
    const int c2 = (t & 127) * 2;
    const int rq = t >> 7;              // 0..7
    float wA = W0[(size_t)512*HID + c2],  wBv = W0[(size_t)512*HID + c2 + 1];
    float xA = W0[(size_t)513*HID + c2],  xB = W0[(size_t)513*HID + c2 + 1];
    float yA = W0[(size_t)514*HID + c2],  yB = W0[(size_t)514*HID + c2 + 1];
    float zA = W0[(size_t)515*HID + c2],  zB = W0[(size_t)515*HID + c2 + 1];
    const float* Pb = P + (size_t)b * NPOS * HID;
    #pragma unroll 4
    for (int i = 0; i < 32; ++i) {
      const int e = rq*32 + i;
      const float* pr = Pb + (size_t)lin_s[e]*HID + c2;
      float vA = pr[0] + r0_s[e]*wA + r1_s[e]*xA + rc0_s[e]*yA + rc1_s[e]*zA;
      float vB = pr[1] + r0_s[e]*wBv + r1_s[e]*xB + rc0_s[e]*yB + rc1_s[e]*zB;
      unsigned int pk = (unsigned int)f2bf(fmaxf(vA, 0.0f)) |
                        ((unsigned int)f2bf(fmaxf(vB, 0.0f)) << 16);
      *(unsigned int*)(lds + (e << 9) + ((c2*2) ^ ((e & 7) << 4))) = pk;
    }
  }
  __syncthreads();                      // act ready; L1c0 DMA drained

  // ---- Layers 1..3 ---------------------------------------------------------
  f32x4 acc[16];
  LAYER3(0,      131072, 0);  LAYER_WB3(b1);   // L1 (stages L2c0 at kc7)
  LAYER3(131072, 262144, 0);  LAYER_WB3(b2);   // L2 (stages L3c0 at kc7)
  LAYER3(262144, 0, 1);                        // L3 (no next)

  // ---- fused final layer: p[mt][o] = sum_n relu(acc+b3) * W4t[o][n] -------
  {
    float p[4][3];
    #pragma unroll
    for (int mt = 0; mt < 4; ++mt)
      { p[mt][0] = 0.f; p[mt][1] = 0.f; p[mt][2] = 0.f; }
    #pragma unroll
    for (int nt = 0; nt < 4; ++nt) {
      f32x4 bv  = *(const f32x4*)&b3[nW + nt*16 + lk*4];
      f32x4 w40 = *(const f32x4*)&w4t[      nW + nt*16 + lk*4];
      f32x4 w41 = *(const f32x4*)&w4t[256 + nW + nt*16 + lk*4];
      f32x4 w42 = *(const f32x4*)&w4t[512 + nW + nt*16 + lk*4];
      #pragma unroll
      for (int mt = 0; mt < 4; ++mt) {
        f32x4 a = acc[mt*4 + nt];
        #pragma unroll
        for (int j = 0; j < 4; ++j) {
          float v = fmaxf(a[j] + bv[j], 0.f);
          p[mt][0] += v * w40[j];
          p[mt][1] += v * w41[j];
          p[mt][2] += v * w42[j];
        }
      }
    }
    #pragma unroll
    for (int mt = 0; mt < 4; ++mt)
      #pragma unroll
      for (int o = 0; o < 3; ++o) {
        float s = p[mt][o];
        s += __shfl_xor(s, 16);
        s += __shfl_xor(s, 32);
        p[mt][o] = s;
      }
    if (lk == 0) {                       // lanes 0..15: one writer per m-col
      #pragma unroll
      for (int mt = 0; mt < 4; ++mt) {
        const int m = m0 + mt*16 + lr;
        predp[wc*768 + m*3 + 0] = p[mt][0];
        predp[wc*768 + m*3 + 1] = p[mt][1];
        predp[wc*768 + m*3 + 2] = p[mt][2];
      }
    }
  }
  __syncthreads();

  // ---- blend: pred[e][o] = b4 + sum_wc partials; w[s] = area[3-s]/tot -----
  if (t < TQ*3) {
    const int q = t / 3, o = t - (t/3)*3;
    const int eb = q*4;
    const size_t cbase = (((size_t)b << 16) + (q0 + q)) * 2;
    float c0 = coord[cbase + 0];
    float c1 = coord[cbase + 1];
    float ar[4];
    #pragma unroll
    for (int s = 0; s < 4; ++s) {
      float r0, r1; int ir, ic;
      rel_calc(c0, c1, s, r0, r1, ir, ic);
      ar[s] = __fadd_rn(fabsf(__fmul_rn(r0, r1)), 1e-9f);
    }
    float pe[4];
    #pragma unroll
    for (int s = 0; s < 4; ++s) {
      const int e = eb + s;
      pe[s] = b4[o] + predp[e*3 + o] + predp[768 + e*3 + o]
                    + predp[1536 + e*3 + o] + predp[2304 + e*3 + o];
    }
    float tot = ((ar[0] + ar[1]) + ar[2]) + ar[3];
    float rv = (pe[0]*ar[3] + pe[1]*ar[2] + pe[2]*ar[1] + pe[3]*ar[0]) / tot;
    out[(((size_t)b << 16) + (q0 + q))*3 + o] = rv;
  }
}

// ---------------------------------------------------------------------------
extern "C" void kernel_launch(void* const* d_in, const int* in_sizes, int n_in,
                              void* d_out, int out_size, void* d_ws, size_t ws_size,
                              hipStream_t stream)
{
  const float* feat  = (const float*)d_in[0];
  const float* coord = (const float*)d_in[1];
  const float* cell  = (const float*)d_in[2];
  const float* W0    = (const float*)d_in[3];
  const float* b0    = (const float*)d_in[4];
  const float* W1    = (const float*)d_in[5];
  const float* b1    = (const float*)d_in[6];
  const float* W2    = (const float*)d_in[7];
  const float* b2    = (const float*)d_in[8];
  const float* W3    = (const float*)d_in[9];
  const float* b3    = (const float*)d_in[10];
  const float* W4    = (const float*)d_in[11];
  const float* b4    = (const float*)d_in[12];
  float* outp = (float*)d_out;

  // ws layout: P f32 [2*2304*256] = 4,718,592 B | W image 3*8*16384 = 393,216 B
  //            | W4t f32 3*256 = 3,072 B
  float*         P    = (float*)d_ws;
  unsigned char* imgp = (unsigned char*)d_ws + 4718592;
  float*         w4tp = (float*)((unsigned char*)d_ws + 4718592 + 393216);

  hipLaunchKernelGGL(liif_precompute, dim3(2*(NPOS/4)), dim3(256), 0, stream,
                     feat, W0, b0, P);
  hipLaunchKernelGGL(liif_convert, dim3(25), dim3(256), 0, stream,
                     W1, W2, W3, W4, imgp, w4tp);
  hipLaunchKernelGGL(liif_main, dim3(2048), dim3(1024), 0, stream,
                     coord, cell, P, W0, imgp, b1, b2, b3, b4, w4tp, outp);
}

// Round 11
// 318.403 us; speedup vs baseline: 1.8199x; 1.0076x over previous
//
#include <hip/hip_runtime.h>
#include <math.h>

#define HH    48
#define CFEAT 512
#define HID   256
#define NPOS  (HH*HH)   // 2304
#define TQ    64        // queries per block
#define NEV   256       // evals per block = TQ*4

typedef __attribute__((ext_vector_type(8))) short bf16x8;
typedef __attribute__((ext_vector_type(4))) float f32x4;

static __device__ __forceinline__ unsigned short f2bf(float x) {
  unsigned int u = __float_as_uint(x);
  u += 0x7fffu + ((u >> 16) & 1u);     // RNE
  return (unsigned short)(u >> 16);
}

// index/rel math shared (bit-exact) by Phase A and blend-area recompute
static __device__ __forceinline__ void rel_calc(float c0, float c1, int s,
                                                float& r0, float& r1,
                                                int& ir, int& ic) {
  float vx = (s & 2) ? 1.0f : -1.0f;
  float vy = (s & 1) ? 1.0f : -1.0f;
  const float RXY = (float)(1.0/48.0);
  const float CLO = (float)(-1.0 + 1e-6);
  const float CHI = (float)( 1.0 - 1e-6);
  float gx = __fadd_rn(c0, __fadd_rn(__fmul_rn(vx, RXY), 1e-6f));
  float gy = __fadd_rn(c1, __fadd_rn(__fmul_rn(vy, RXY), 1e-6f));
  gx = fminf(fmaxf(gx, CLO), CHI);
  gy = fminf(fmaxf(gy, CLO), CHI);
  float xr = __fmul_rn(__fsub_rn(__fmul_rn(__fadd_rn(gx, 1.0f), 48.0f), 1.0f), 0.5f);
  float xc = __fmul_rn(__fsub_rn(__fmul_rn(__fadd_rn(gy, 1.0f), 48.0f), 1.0f), 0.5f);
  ir = (int)rintf(xr); ir = ir < 0 ? 0 : (ir > HH-1 ? HH-1 : ir);
  ic = (int)rintf(xc); ic = ic < 0 ? 0 : (ic > HH-1 ? HH-1 : ic);
  const float T2 = (float)(2.0/48.0);
  float qcr = __fsub_rn(__fmul_rn(__fadd_rn((float)ir, 0.5f), T2), 1.0f);
  float qcc = __fsub_rn(__fmul_rn(__fadd_rn((float)ic, 0.5f), T2), 1.0f);
  r0 = __fmul_rn(__fsub_rn(c0, qcr), 48.0f);
  r1 = __fmul_rn(__fsub_rn(c1, qcc), 48.0f);
}

// ---------------------------------------------------------------------------
// Kernel 1: P[b][pos][n] = b0[n] + sum_c feat[b][c][pos] * W0[c][n]  (fp32)
// ---------------------------------------------------------------------------
__global__ __launch_bounds__(256) void liif_precompute(
    const float* __restrict__ feat, const float* __restrict__ W0,
    const float* __restrict__ b0, float* __restrict__ P)
{
  int blk = blockIdx.x;                 // 0..1151
  int b   = blk / (NPOS/4);
  int p0  = (blk - b*(NPOS/4)) * 4;
  int n   = threadIdx.x;
  const float* f = feat + (size_t)b * CFEAT * NPOS + p0;
  float bias = b0[n];
  float a0 = bias, a1 = bias, a2 = bias, a3 = bias;
  #pragma unroll 4
  for (int c = 0; c < CFEAT; ++c) {
    float w = W0[c*HID + n];
    const float* fr = f + (size_t)c * NPOS;
    a0 += fr[0]*w; a1 += fr[1]*w; a2 += fr[2]*w; a3 += fr[3]*w;
  }
  float* Pp = P + ((size_t)b*NPOS + p0)*HID + n;
  Pp[0*HID] = a0; Pp[1*HID] = a1; Pp[2*HID] = a2; Pp[3*HID] = a3;
}

// ---------------------------------------------------------------------------
// Kernel 2: build pre-permuted W image for linear global_load_lds staging.
// Chunk (l,kc) = 16 KB; 16-B unit p (0..1023):
//   wc = p>>8, nt = (p>>6)&3, lane = p&63, lr = lane&15, lk = lane>>4
//   n = wc*64 + nt*16 + lr ; unit holds Wt[n][kc*32 + lk*8 .. +8]
// Read addr for (wc, lane, nt) = wc*4096 + nt*1024 + lane*16 -> consecutive
// lanes hit consecutive 16-B units => all 8 bank groups per 8-lane batch
// (conflict-free). Also W4 -> f32 W4t[o][k].
// ---------------------------------------------------------------------------
__global__ __launch_bounds__(256) void liif_convert(
    const float* __restrict__ W1, const float* __restrict__ W2,
    const float* __restrict__ W3, const float* __restrict__ W4,
    unsigned char* __restrict__ img, float* __restrict__ w4t)
{
  int blk = blockIdx.x, t = threadIdx.x;
  if (blk < 24) {
    int l = blk >> 3, kc = blk & 7;
    const float* W = (l == 0) ? W1 : (l == 1) ? W2 : W3;
    unsigned short* dst = (unsigned short*)(img + (size_t)blk * 16384);
    #pragma unroll 1
    for (int s = 0; s < 4; ++s) {
      int p    = t + s*256;
      int wc   = p >> 8;
      int nt   = (p >> 6) & 3;
      int lane = p & 63;
      int lr   = lane & 15, lk = lane >> 4;
      int n    = wc*64 + nt*16 + lr;
      int k0   = kc*32 + lk*8;
      #pragma unroll
      for (int j = 0; j < 8; ++j)
        dst[p*8 + j] = f2bf(W[(k0 + j)*256 + n]);
    }
  } else {
    for (int o = 0; o < 3; ++o) w4t[o*256 + t] = W4[t*3 + o];
  }
}

// ---------------------------------------------------------------------------
// Kernel 3: fused main. 256 evals/block, 1024 thr / 16 waves (grid 4x4),
// wave tile 64x64. act: XOR-swizzled [256 rows][512 B] (131 KB).
// W: global_load_lds DMA (zero staging VGPRs), double-buffered 16 KB chunks,
// conflict-free lane-ordered image. One barrier per kstep.
// ---------------------------------------------------------------------------
// LDS map:
//   [0, 131072)        act (swizzled). After L3: predp overlay (12 KB).
//   [131072, 147456)   wbuf0
//   [147456, 163840)   wbuf1; first 5 KB = {lin_s,r0,r1,rc0,rc1} in Phase A/B.

#define LDSA   0
#define LDSW   131072
#define LDSM   147456

#define MF(A, B, C) __builtin_amdgcn_mfma_f32_16x16x32_bf16((A), (B), (C), 0, 0, 0)

#define AS1(p) ((const __attribute__((address_space(1))) void*)(unsigned long long)(const void*)(p))
#define AS3(p) ((__attribute__((address_space(3))) void*)(unsigned int)(unsigned long long)(void*)(p))

// DMA one 16 KB chunk: each thread 16 B; wave w covers [w*1024, +1024)
#define STAGE(LOFF, NKC, BUF) \
  __builtin_amdgcn_global_load_lds( \
      AS1(img + (LOFF) + (NKC)*16384 + sgoff), \
      AS3(lds + LDSW + (BUF)*16384 + swoff), 16, 0, 0)

// one K=32 step: optional DMA of next chunk, 4 W + 4 act reads, 16 MFMA,
// barrier (compiler-emitted vmcnt(0) drains the DMA before s_barrier).
#define KSTEP(KC, HASN, NLOFF, NKC) do {                                      \
    if (HASN) STAGE(NLOFF, NKC, (((KC)+1)&1));                                \
    const unsigned char* wb_ = lds + LDSW + (((KC)&1)*16384) + lwoff;         \
    bf16x8 w0_ = *(const bf16x8*)(wb_ + 0);                                   \
    bf16x8 w1_ = *(const bf16x8*)(wb_ + 1024);                                \
    bf16x8 w2_ = *(const bf16x8*)(wb_ + 2048);                                \
    bf16x8 w3_ = *(const bf16x8*)(wb_ + 3072);                                \
    const int ko_ = (((KC) << 6) ^ xb6);                                      \
    bf16x8 a0_ = *(const bf16x8*)(lds + rb0 + ko_);                           \
    bf16x8 a1_ = *(const bf16x8*)(lds + rb1 + ko_);                           \
    bf16x8 a2_ = *(const bf16x8*)(lds + rb2 + ko_);                           \
    bf16x8 a3_ = *(const bf16x8*)(lds + rb3 + ko_);                           \
    acc[0]  = MF(w0_, a0_, acc[0]);  acc[1]  = MF(w1_, a0_, acc[1]);          \
    acc[2]  = MF(w2_, a0_, acc[2]);  acc[3]  = MF(w3_, a0_, acc[3]);          \
    acc[4]  = MF(w0_, a1_, acc[4]);  acc[5]  = MF(w1_, a1_, acc[5]);          \
    acc[6]  = MF(w2_, a1_, acc[6]);  acc[7]  = MF(w3_, a1_, acc[7]);          \
    acc[8]  = MF(w0_, a2_, acc[8]);  acc[9]  = MF(w1_, a2_, acc[9]);          \
    acc[10] = MF(w2_, a2_, acc[10]); acc[11] = MF(w3_, a2_, acc[11]);         \
    acc[12] = MF(w0_, a3_, acc[12]); acc[13] = MF(w1_, a3_, acc[13]);         \
    acc[14] = MF(w2_, a3_, acc[14]); acc[15] = MF(w3_, a3_, acc[15]);         \
    __syncthreads();                                                          \
  } while (0)

// full layer: entering, wbuf[0] holds this layer's chunk0.
#define LAYER3(LOFF, NLOFF, LAST) do {                                        \
    _Pragma("unroll")                                                         \
    for (int i_ = 0; i_ < 16; ++i_) acc[i_] = (f32x4){0.f, 0.f, 0.f, 0.f};    \
    KSTEP(0, 1, (LOFF), 1); KSTEP(1, 1, (LOFF), 2);                           \
    KSTEP(2, 1, (LOFF), 3); KSTEP(3, 1, (LOFF), 4);                           \
    KSTEP(4, 1, (LOFF), 5); KSTEP(5, 1, (LOFF), 6);                           \
    KSTEP(6, 1, (LOFF), 7); KSTEP(7, !(LAST), (NLOFF), 0);                    \
  } while (0)

// bias+relu -> bf16 writeback into swizzled act, then barrier
#define LAYER_WB3(BIAS) do {                                                  \
    _Pragma("unroll")                                                         \
    for (int nt_ = 0; nt_ < 4; ++nt_) {                                       \
      f32x4 bv_ = *(const f32x4*)&(BIAS)[nW + nt_*16 + lk*4];                 \
      const int cb_ = (cwb + nt_*32) ^ xwb;                                   \
      _Pragma("unroll")                                                       \
      for (int mt_ = 0; mt_ < 4; ++mt_) {                                     \
        f32x4 a_ = acc[mt_*4 + nt_];                                          \
        unsigned int lo_ = (unsigned int)f2bf(fmaxf(a_[0] + bv_[0], 0.f))     \
                         | ((unsigned int)f2bf(fmaxf(a_[1] + bv_[1], 0.f)) << 16); \
        unsigned int hi_ = (unsigned int)f2bf(fmaxf(a_[2] + bv_[2], 0.f))     \
                         | ((unsigned int)f2bf(fmaxf(a_[3] + bv_[3], 0.f)) << 16); \
        *(uint2*)(lds + ((m0 + mt_*16 + lr) << 9) + cb_) = make_uint2(lo_, hi_); \
      }                                                                       \
    }                                                                         \
    __syncthreads();                                                          \
  } while (0)

__global__ __launch_bounds__(1024, 4)
__attribute__((amdgpu_waves_per_eu(4, 4)))
void liif_main(
    const float* __restrict__ coord, const float* __restrict__ cell,
    const float* __restrict__ P,  const float* __restrict__ W0,
    const unsigned char* __restrict__ img,
    const float* __restrict__ b1, const float* __restrict__ b2,
    const float* __restrict__ b3, const float* __restrict__ b4,
    const float* __restrict__ w4t, float* __restrict__ out)
{
  __shared__ __align__(16) unsigned char lds[163840];
  int*   lin_s = (int*)  (lds + LDSM);
  float* r0_s  = (float*)(lds + LDSM + 1024);
  float* r1_s  = (float*)(lds + LDSM + 2048);
  float* rc0_s = (float*)(lds + LDSM + 3072);
  float* rc1_s = (float*)(lds + LDSM + 4096);
  float* predp = (float*)lds;           // [4 wc][256 m][3 o] = 12 KB overlay

  const int t   = threadIdx.x;
  const int blk = blockIdx.x;
  const int b   = blk >> 10;            // 1024 blocks per batch
  const int q0  = (blk & 1023) * TQ;

  const int lane = t & 63;
  const int w    = t >> 6;              // 0..15
  const int m0   = (w >> 2) * 64;       // wave row base
  const int wc   = w & 3;
  const int nW   = wc * 64;             // wave col base
  const int lr   = lane & 15;
  const int lk   = lane >> 4;

  // DMA staging offsets
  const size_t sgoff = (size_t)t * 16;  // per-lane global offset in chunk
  const int    swoff = w * 1024;        // wave-uniform LDS slice base

  // W-read base: lane-ordered image => conflict-free (+ nt*1024 per frag)
  const int lwoff = wc*4096 + lane*16;
  // act-read bases (swizzle: colbyte ^ ((row&7)<<4), split into xl | xb6)
  const int xl  = (lr & 3) << 4;
  const int xb6 = ((lr >> 2) & 1) << 6;
  const int rb0 = ((m0 +  0 + lr) << 9) + ((lk << 4) ^ xl);
  const int rb1 = ((m0 + 16 + lr) << 9) + ((lk << 4) ^ xl);
  const int rb2 = ((m0 + 32 + lr) << 9) + ((lk << 4) ^ xl);
  const int rb3 = ((m0 + 48 + lr) << 9) + ((lk << 4) ^ xl);
  // writeback constants
  const int cwb = wc*128 + lk*8;
  const int xwb = (lr & 7) << 4;

  // ---- Phase A: indices + rel coords into misc (wbuf1 region) -------------
  if (t < NEV) {
    const int e = t;
    const int q = q0 + (e >> 2);
    const int s = e & 3;                // [(-1,-1),(-1,1),(1,-1),(1,1)]
    const size_t cbase = (((size_t)b << 16) + q) * 2;
    float c0 = coord[cbase + 0];
    float c1 = coord[cbase + 1];
    float r0, r1; int ir, ic;
    rel_calc(c0, c1, s, r0, r1, ir, ic);
    lin_s[e] = ir*HH + ic;
    r0_s[e] = r0; r1_s[e] = r1;
    rc0_s[e] = __fmul_rn(cell[cbase + 0], 48.0f);
    rc1_s[e] = __fmul_rn(cell[cbase + 1], 48.0f);
  }
  __syncthreads();

  // issue L1 chunk0 DMA early (drained by Phase B's ending barrier)
  STAGE(0, 0, 0);

  // ---- Phase B: h0 -> swizzled act. 1024 thr: 128 col-pairs x 8 row-octs --
  {
    const int c2 = (t & 127) * 2;
    const int rq = t >> 7;              // 0..7
    float wA = W0[(size_t)512*HID + c2],  wBv = W0[(size_t)512*HID + c2 + 1];
    float xA = W0[(size_t)513*HID + c2],  xB = W0[(size_t)513*HID + c2 + 1];
    float yA = W0[(size_t)514*HID + c2],  yB = W0[(size_t)514*HID + c2 + 1];
    float zA = W0[(size_t)515*HID + c2],  zB = W0[(size_t)515*HID + c2 + 1];
    const float* Pb = P + (size_t)b * NPOS * HID;
    #pragma unroll 4
    for (int i = 0; i < 32; ++i) {
      const int e = rq*32 + i;
      const float* pr = Pb + (size_t)lin_s[e]*HID + c2;
      float vA = pr[0] + r0_s[e]*wA + r1_s[e]*xA + rc0_s[e]*yA + rc1_s[e]*zA;
      float vB = pr[1] + r0_s[e]*wBv + r1_s[e]*xB + rc0_s[e]*yB + rc1_s[e]*zB;
      unsigned int pk = (unsigned int)f2bf(fmaxf(vA, 0.0f)) |
                        ((unsigned int)f2bf(fmaxf(vB, 0.0f)) << 16);
      *(unsigned int*)(lds + (e << 9) + ((c2*2) ^ ((e & 7) << 4))) = pk;
    }
  }
  __syncthreads();                      // act ready; L1c0 DMA drained

  // ---- Layers 1..3 ---------------------------------------------------------
  f32x4 acc[16];
  LAYER3(0,      131072, 0);  LAYER_WB3(b1);   // L1 (stages L2c0 at kc7)
  LAYER3(131072, 262144, 0);  LAYER_WB3(b2);   // L2 (stages L3c0 at kc7)
  LAYER3(262144, 0, 1);                        // L3 (no next)

  // ---- fused final layer, per-o passes (low live-reg count, no spill) -----
  {
    #pragma unroll
    for (int o = 0; o < 3; ++o) {
      float p4[4] = {0.f, 0.f, 0.f, 0.f};
      #pragma unroll
      for (int nt = 0; nt < 4; ++nt) {
        f32x4 bv = *(const f32x4*)&b3[nW + nt*16 + lk*4];
        f32x4 wv = *(const f32x4*)&w4t[o*256 + nW + nt*16 + lk*4];
        #pragma unroll
        for (int mt = 0; mt < 4; ++mt) {
          f32x4 a = acc[mt*4 + nt];
          #pragma unroll
          for (int j = 0; j < 4; ++j)
            p4[mt] += fmaxf(a[j] + bv[j], 0.f) * wv[j];
        }
      }
      #pragma unroll
      for (int mt = 0; mt < 4; ++mt) {
        float s = p4[mt];
        s += __shfl_xor(s, 16);
        s += __shfl_xor(s, 32);
        p4[mt] = s;
      }
      if (lk == 0) {
        #pragma unroll
        for (int mt = 0; mt < 4; ++mt)
          predp[wc*768 + (m0 + mt*16 + lr)*3 + o] = p4[mt];
      }
    }
  }
  __syncthreads();

  // ---- blend: pred[e][o] = b4 + sum_wc partials; w[s] = area[3-s]/tot -----
  if (t < TQ*3) {
    const int q = t / 3, o = t - (t/3)*3;
    const int eb = q*4;
    const size_t cbase = (((size_t)b << 16) + (q0 + q)) * 2;
    float c0 = coord[cbase + 0];
    float c1 = coord[cbase + 1];
    float ar[4];
    #pragma unroll
    for (int s = 0; s < 4; ++s) {
      float r0, r1; int ir, ic;
      rel_calc(c0, c1, s, r0, r1, ir, ic);
      ar[s] = __fadd_rn(fabsf(__fmul_rn(r0, r1)), 1e-9f);
    }
    float pe[4];
    #pragma unroll
    for (int s = 0; s < 4; ++s) {
      const int e = eb + s;
      pe[s] = b4[o] + predp[e*3 + o] + predp[768 + e*3 + o]
                    + predp[1536 + e*3 + o] + predp[2304 + e*3 + o];
    }
    float tot = ((ar[0] + ar[1]) + ar[2]) + ar[3];
    float rv = (pe[0]*ar[3] + pe[1]*ar[2] + pe[2]*ar[1] + pe[3]*ar[0]) / tot;
    out[(((size_t)b << 16) + (q0 + q))*3 + o] = rv;
  }
}

// ---------------------------------------------------------------------------
extern "C" void kernel_launch(void* const* d_in, const int* in_sizes, int n_in,
                              void* d_out, int out_size, void* d_ws, size_t ws_size,
                              hipStream_t stream)
{
  const float* feat  = (const float*)d_in[0];
  const float* coord = (const float*)d_in[1];
  const float* cell  = (const float*)d_in[2];
  const float* W0    = (const float*)d_in[3];
  const float* b0    = (const float*)d_in[4];
  const float* W1    = (const float*)d_in[5];
  const float* b1    = (const float*)d_in[6];
  const float* W2    = (const float*)d_in[7];
  const float* b2    = (const float*)d_in[8];
  const float* W3    = (const float*)d_in[9];
  const float* b3    = (const float*)d_in[10];
  const float* W4    = (const float*)d_in[11];
  const float* b4    = (const float*)d_in[12];
  float* outp = (float*)d_out;

  // ws layout: P f32 [2*2304*256] = 4,718,592 B | W image 3*8*16384 = 393,216 B
  //            | W4t f32 3*256 = 3,072 B
  float*         P    = (float*)d_ws;
  unsigned char* imgp = (unsigned char*)d_ws + 4718592;
  float*         w4tp = (float*)((unsigned char*)d_ws + 4718592 + 393216);

  hipLaunchKernelGGL(liif_precompute, dim3(2*(NPOS/4)), dim3(256), 0, stream,
                     feat, W0, b0, P);
  hipLaunchKernelGGL(liif_convert, dim3(25), dim3(256), 0, stream,
                     W1, W2, W3, W4, imgp, w4tp);
  hipLaunchKernelGGL(liif_main, dim3(2048), dim3(1024), 0, stream,
                     coord, cell, P, W0, imgp, b1, b2, b3, b4, w4tp, outp);
}

// Round 12
// 284.096 us; speedup vs baseline: 2.0397x; 1.1208x over previous
//
#include <hip/hip_runtime.h>
#include <hip/hip_bf16.h>
#include <math.h>

#define HH    48
#define CFEAT 512
#define HID   256
#define NPOS  (HH*HH)   // 2304
#define TQ    64        // queries per block
#define NEV   256       // evals per block = TQ*4

typedef __attribute__((ext_vector_type(8))) short bf16x8;
typedef __attribute__((ext_vector_type(4))) float f32x4;

static __device__ __forceinline__ unsigned short f2bf(float x) {
  unsigned int u = __float_as_uint(x);
  u += 0x7fffu + ((u >> 16) & 1u);     // RNE
  return (unsigned short)(u >> 16);
}

// packed f32x2 -> bf16x2 via v_cvt_pk_bf16_f32 (RNE, low word = first arg)
static __device__ __forceinline__ unsigned int pk2bf(float a, float b) {
  __hip_bfloat162 h2 = __float22bfloat162_rn(make_float2(a, b));
  unsigned int u; __builtin_memcpy(&u, &h2, 4); return u;
}

// index/rel math shared (bit-exact) by Phase A and blend-area recompute
static __device__ __forceinline__ void rel_calc(float c0, float c1, int s,
                                                float& r0, float& r1,
                                                int& ir, int& ic) {
  float vx = (s & 2) ? 1.0f : -1.0f;
  float vy = (s & 1) ? 1.0f : -1.0f;
  const float RXY = (float)(1.0/48.0);
  const float CLO = (float)(-1.0 + 1e-6);
  const float CHI = (float)( 1.0 - 1e-6);
  float gx = __fadd_rn(c0, __fadd_rn(__fmul_rn(vx, RXY), 1e-6f));
  float gy = __fadd_rn(c1, __fadd_rn(__fmul_rn(vy, RXY), 1e-6f));
  gx = fminf(fmaxf(gx, CLO), CHI);
  gy = fminf(fmaxf(gy, CLO), CHI);
  float xr = __fmul_rn(__fsub_rn(__fmul_rn(__fadd_rn(gx, 1.0f), 48.0f), 1.0f), 0.5f);
  float xc = __fmul_rn(__fsub_rn(__fmul_rn(__fadd_rn(gy, 1.0f), 48.0f), 1.0f), 0.5f);
  ir = (int)rintf(xr); ir = ir < 0 ? 0 : (ir > HH-1 ? HH-1 : ir);
  ic = (int)rintf(xc); ic = ic < 0 ? 0 : (ic > HH-1 ? HH-1 : ic);
  const float T2 = (float)(2.0/48.0);
  float qcr = __fsub_rn(__fmul_rn(__fadd_rn((float)ir, 0.5f), T2), 1.0f);
  float qcc = __fsub_rn(__fmul_rn(__fadd_rn((float)ic, 0.5f), T2), 1.0f);
  r0 = __fmul_rn(__fsub_rn(c0, qcr), 48.0f);
  r1 = __fmul_rn(__fsub_rn(c1, qcc), 48.0f);
}

// ---------------------------------------------------------------------------
// Kernel 1: P[b][pos][n] = b0[n] + sum_c feat[b][c][pos] * W0[c][n]  (fp32)
// ---------------------------------------------------------------------------
__global__ __launch_bounds__(256) void liif_precompute(
    const float* __restrict__ feat, const float* __restrict__ W0,
    const float* __restrict__ b0, float* __restrict__ P)
{
  int blk = blockIdx.x;                 // 0..1151
  int b   = blk / (NPOS/4);
  int p0  = (blk - b*(NPOS/4)) * 4;
  int n   = threadIdx.x;
  const float* f = feat + (size_t)b * CFEAT * NPOS + p0;
  float bias = b0[n];
  float a0 = bias, a1 = bias, a2 = bias, a3 = bias;
  #pragma unroll 4
  for (int c = 0; c < CFEAT; ++c) {
    float w = W0[c*HID + n];
    const float* fr = f + (size_t)c * NPOS;
    a0 += fr[0]*w; a1 += fr[1]*w; a2 += fr[2]*w; a3 += fr[3]*w;
  }
  float* Pp = P + ((size_t)b*NPOS + p0)*HID + n;
  Pp[0*HID] = a0; Pp[1*HID] = a1; Pp[2*HID] = a2; Pp[3*HID] = a3;
}

// ---------------------------------------------------------------------------
// Kernel 2: build pre-permuted W image for linear global_load_lds staging.
// Chunk (l,kc) = 16 KB; 16-B unit p (0..1023):
//   wc = p>>8, nt = (p>>6)&3, lane = p&63, lr = lane&15, lk = lane>>4
//   n = wc*64 + nt*16 + lr ; unit holds Wt[n][kc*32 + lk*8 .. +8]
// Read addr (wc, lane, nt) = wc*4096 + nt*1024 + lane*16 -> conflict-free.
// Also W4 -> f32 W4t[o][k].
// ---------------------------------------------------------------------------
__global__ __launch_bounds__(256) void liif_convert(
    const float* __restrict__ W1, const float* __restrict__ W2,
    const float* __restrict__ W3, const float* __restrict__ W4,
    unsigned char* __restrict__ img, float* __restrict__ w4t)
{
  int blk = blockIdx.x, t = threadIdx.x;
  if (blk < 24) {
    int l = blk >> 3, kc = blk & 7;
    const float* W = (l == 0) ? W1 : (l == 1) ? W2 : W3;
    unsigned short* dst = (unsigned short*)(img + (size_t)blk * 16384);
    #pragma unroll 1
    for (int s = 0; s < 4; ++s) {
      int p    = t + s*256;
      int wc   = p >> 8;
      int nt   = (p >> 6) & 3;
      int lane = p & 63;
      int lr   = lane & 15, lk = lane >> 4;
      int n    = wc*64 + nt*16 + lr;
      int k0   = kc*32 + lk*8;
      #pragma unroll
      for (int j = 0; j < 8; ++j)
        dst[p*8 + j] = f2bf(W[(k0 + j)*256 + n]);
    }
  } else {
    for (int o = 0; o < 3; ++o) w4t[o*256 + t] = W4[t*3 + o];
  }
}

// ---------------------------------------------------------------------------
// Kernel 3: fused main. 256 evals/block, 1024 thr / 16 waves (grid 4x4),
// wave tile 64x64. act: XOR-swizzled [256 rows][512 B] (131 KB).
// W: global_load_lds DMA, double-buffered 16 KB chunks, conflict-free image.
// Phase B: wave-per-row coalesced P loads + packed rel4 broadcast + cvt_pk.
// ---------------------------------------------------------------------------
// LDS map:
//   [0, 131072)        act (swizzled). After L3: predp overlay (12 KB).
//   [131072, 147456)   wbuf0
//   [147456, 163840)   wbuf1; first 5 KB = {lin_s, rel4} in Phase A/B.

#define LDSA   0
#define LDSW   131072
#define LDSM   147456

#define MF(A, B, C) __builtin_amdgcn_mfma_f32_16x16x32_bf16((A), (B), (C), 0, 0, 0)

#define AS1(p) ((const __attribute__((address_space(1))) void*)(unsigned long long)(const void*)(p))
#define AS3(p) ((__attribute__((address_space(3))) void*)(unsigned int)(unsigned long long)(void*)(p))

// DMA one 16 KB chunk: each thread 16 B; wave w covers [w*1024, +1024)
#define STAGE(LOFF, NKC, BUF) \
  __builtin_amdgcn_global_load_lds( \
      AS1(img + (LOFF) + (NKC)*16384 + sgoff), \
      AS3(lds + LDSW + (BUF)*16384 + swoff), 16, 0, 0)

// one K=32 step: optional DMA of next chunk, 4 W + 4 act reads, 16 MFMA,
// barrier (compiler-emitted vmcnt(0) drains the DMA before s_barrier).
#define KSTEP(KC, HASN, NLOFF, NKC) do {                                      \
    if (HASN) STAGE(NLOFF, NKC, (((KC)+1)&1));                                \
    const unsigned char* wb_ = lds + LDSW + (((KC)&1)*16384) + lwoff;         \
    bf16x8 w0_ = *(const bf16x8*)(wb_ + 0);                                   \
    bf16x8 w1_ = *(const bf16x8*)(wb_ + 1024);                                \
    bf16x8 w2_ = *(const bf16x8*)(wb_ + 2048);                                \
    bf16x8 w3_ = *(const bf16x8*)(wb_ + 3072);                                \
    const int ko_ = (((KC) << 6) ^ xb6);                                      \
    bf16x8 a0_ = *(const bf16x8*)(lds + rb0 + ko_);                           \
    bf16x8 a1_ = *(const bf16x8*)(lds + rb1 + ko_);                           \
    bf16x8 a2_ = *(const bf16x8*)(lds + rb2 + ko_);                           \
    bf16x8 a3_ = *(const bf16x8*)(lds + rb3 + ko_);                           \
    acc[0]  = MF(w0_, a0_, acc[0]);  acc[1]  = MF(w1_, a0_, acc[1]);          \
    acc[2]  = MF(w2_, a0_, acc[2]);  acc[3]  = MF(w3_, a0_, acc[3]);          \
    acc[4]  = MF(w0_, a1_, acc[4]);  acc[5]  = MF(w1_, a1_, acc[5]);          \
    acc[6]  = MF(w2_, a1_, acc[6]);  acc[7]  = MF(w3_, a1_, acc[7]);          \
    acc[8]  = MF(w0_, a2_, acc[8]);  acc[9]  = MF(w1_, a2_, acc[9]);          \
    acc[10] = MF(w2_, a2_, acc[10]); acc[11] = MF(w3_, a2_, acc[11]);         \
    acc[12] = MF(w0_, a3_, acc[12]); acc[13] = MF(w1_, a3_, acc[13]);         \
    acc[14] = MF(w2_, a3_, acc[14]); acc[15] = MF(w3_, a3_, acc[15]);         \
    __syncthreads();                                                          \
  } while (0)

// full layer: entering, wbuf[0] holds this layer's chunk0.
#define LAYER3(LOFF, NLOFF, LAST) do {                                        \
    _Pragma("unroll")                                                         \
    for (int i_ = 0; i_ < 16; ++i_) acc[i_] = (f32x4){0.f, 0.f, 0.f, 0.f};    \
    KSTEP(0, 1, (LOFF), 1); KSTEP(1, 1, (LOFF), 2);                           \
    KSTEP(2, 1, (LOFF), 3); KSTEP(3, 1, (LOFF), 4);                           \
    KSTEP(4, 1, (LOFF), 5); KSTEP(5, 1, (LOFF), 6);                           \
    KSTEP(6, 1, (LOFF), 7); KSTEP(7, !(LAST), (NLOFF), 0);                    \
  } while (0)

// bias+relu -> bf16 writeback into swizzled act via cvt_pk, then barrier
#define LAYER_WB3(BIAS) do {                                                  \
    _Pragma("unroll")                                                         \
    for (int nt_ = 0; nt_ < 4; ++nt_) {                                       \
      f32x4 bv_ = *(const f32x4*)&(BIAS)[nW + nt_*16 + lk*4];                 \
      const int cb_ = (cwb + nt_*32) ^ xwb;                                   \
      _Pragma("unroll")                                                       \
      for (int mt_ = 0; mt_ < 4; ++mt_) {                                     \
        f32x4 a_ = acc[mt_*4 + nt_];                                          \
        unsigned int lo_ = pk2bf(fmaxf(a_[0] + bv_[0], 0.f),                  \
                                 fmaxf(a_[1] + bv_[1], 0.f));                 \
        unsigned int hi_ = pk2bf(fmaxf(a_[2] + bv_[2], 0.f),                  \
                                 fmaxf(a_[3] + bv_[3], 0.f));                 \
        *(uint2*)(lds + ((m0 + mt_*16 + lr) << 9) + cb_) = make_uint2(lo_, hi_); \
      }                                                                       \
    }                                                                         \
    __syncthreads();                                                          \
  } while (0)

__global__ __launch_bounds__(1024, 4)
__attribute__((amdgpu_waves_per_eu(4, 4)))
void liif_main(
    const float* __restrict__ coord, const float* __restrict__ cell,
    const float* __restrict__ P,  const float* __restrict__ W0,
    const unsigned char* __restrict__ img,
    const float* __restrict__ b1, const float* __restrict__ b2,
    const float* __restrict__ b3, const float* __restrict__ b4,
    const float* __restrict__ w4t, float* __restrict__ out)
{
  __shared__ __align__(16) unsigned char lds[163840];
  int*   lin_s = (int*)  (lds + LDSM);
  f32x4* rel4  = (f32x4*)(lds + LDSM + 1024);
  float* predp = (float*)lds;           // [4 wc][256 m][3 o] = 12 KB overlay

  const int t   = threadIdx.x;
  const int blk = blockIdx.x;
  const int b   = blk >> 10;            // 1024 blocks per batch
  const int q0  = (blk & 1023) * TQ;

  const int lane = t & 63;
  const int w    = t >> 6;              // 0..15
  const int m0   = (w >> 2) * 64;       // wave row base
  const int wc   = w & 3;
  const int nW   = wc * 64;             // wave col base
  const int lr   = lane & 15;
  const int lk   = lane >> 4;

  // DMA staging offsets
  const size_t sgoff = (size_t)t * 16;  // per-lane global offset in chunk
  const int    swoff = w * 1024;        // wave-uniform LDS slice base

  // W-read base: lane-ordered image => conflict-free (+ nt*1024 per frag)
  const int lwoff = wc*4096 + lane*16;
  // act-read bases (swizzle: colbyte ^ ((row&7)<<4), split into xl | xb6)
  const int xl  = (lr & 3) << 4;
  const int xb6 = ((lr >> 2) & 1) << 6;
  const int rb0 = ((m0 +  0 + lr) << 9) + ((lk << 4) ^ xl);
  const int rb1 = ((m0 + 16 + lr) << 9) + ((lk << 4) ^ xl);
  const int rb2 = ((m0 + 32 + lr) << 9) + ((lk << 4) ^ xl);
  const int rb3 = ((m0 + 48 + lr) << 9) + ((lk << 4) ^ xl);
  // writeback constants
  const int cwb = wc*128 + lk*8;
  const int xwb = (lr & 7) << 4;

  // ---- Phase A: indices + packed rel coords into misc (wbuf1 region) ------
  if (t < NEV) {
    const int e = t;
    const int q = q0 + (e >> 2);
    const int s = e & 3;                // [(-1,-1),(-1,1),(1,-1),(1,1)]
    const size_t cbase = (((size_t)b << 16) + q) * 2;
    float c0 = coord[cbase + 0];
    float c1 = coord[cbase + 1];
    float r0, r1; int ir, ic;
    rel_calc(c0, c1, s, r0, r1, ir, ic);
    lin_s[e] = ir*HH + ic;
    rel4[e] = (f32x4){r0, r1,
                      __fmul_rn(cell[cbase + 0], 48.0f),
                      __fmul_rn(cell[cbase + 1], 48.0f)};
  }
  __syncthreads();

  // issue L1 chunk0 DMA early (drained by Phase B's ending barrier)
  STAGE(0, 0, 0);

  // ---- Phase B: h0 -> swizzled act. Wave = one row; thread = 4 cols -------
  {
    const int cg = t & 63;              // col quad: cols cg*4..+3
    const int rq = t >> 6;              // 0..15: rows rq*16..+15
    const float* w0t = W0 + (size_t)512*HID + cg*4;
    f32x4 wr0 = *(const f32x4*)(w0t);
    f32x4 wr1 = *(const f32x4*)(w0t + 256);
    f32x4 wr2 = *(const f32x4*)(w0t + 512);
    f32x4 wr3 = *(const f32x4*)(w0t + 768);
    const float* Pb = P + (size_t)b * NPOS * HID + cg*4;
    const int wb = cg * 8;              // byte col of this quad
    #pragma unroll 2
    for (int i = 0; i < 16; ++i) {
      const int e = rq*16 + i;
      const int lin = lin_s[e];         // dword broadcast
      f32x4 rel = rel4[e];              // b128 broadcast
      f32x4 pv = *(const f32x4*)(Pb + (size_t)lin*HID);   // coalesced 1KB/row
      float v0 = pv[0] + rel[0]*wr0[0] + rel[1]*wr1[0] + rel[2]*wr2[0] + rel[3]*wr3[0];
      float v1 = pv[1] + rel[0]*wr0[1] + rel[1]*wr1[1] + rel[2]*wr2[1] + rel[3]*wr3[1];
      float v2 = pv[2] + rel[0]*wr0[2] + rel[1]*wr1[2] + rel[2]*wr2[2] + rel[3]*wr3[2];
      float v3 = pv[3] + rel[0]*wr0[3] + rel[1]*wr1[3] + rel[2]*wr2[3] + rel[3]*wr3[3];
      unsigned int lo = pk2bf(fmaxf(v0, 0.f), fmaxf(v1, 0.f));
      unsigned int hi = pk2bf(fmaxf(v2, 0.f), fmaxf(v3, 0.f));
      *(uint2*)(lds + (e << 9) + (wb ^ ((e & 7) << 4))) = make_uint2(lo, hi);
    }
  }
  __syncthreads();                      // act ready; L1c0 DMA drained

  // ---- Layers 1..3 ---------------------------------------------------------
  f32x4 acc[16];
  LAYER3(0,      131072, 0);  LAYER_WB3(b1);   // L1 (stages L2c0 at kc7)
  LAYER3(131072, 262144, 0);  LAYER_WB3(b2);   // L2 (stages L3c0 at kc7)
  LAYER3(262144, 0, 1);                        // L3 (no next)

  // ---- fused final layer, per-o passes (low live-reg count) ---------------
  {
    #pragma unroll
    for (int o = 0; o < 3; ++o) {
      float p4[4] = {0.f, 0.f, 0.f, 0.f};
      #pragma unroll
      for (int nt = 0; nt < 4; ++nt) {
        f32x4 bv = *(const f32x4*)&b3[nW + nt*16 + lk*4];
        f32x4 wv = *(const f32x4*)&w4t[o*256 + nW + nt*16 + lk*4];
        #pragma unroll
        for (int mt = 0; mt < 4; ++mt) {
          f32x4 a = acc[mt*4 + nt];
          #pragma unroll
          for (int j = 0; j < 4; ++j)
            p4[mt] += fmaxf(a[j] + bv[j], 0.f) * wv[j];
        }
      }
      #pragma unroll
      for (int mt = 0; mt < 4; ++mt) {
        float s = p4[mt];
        s += __shfl_xor(s, 16);
        s += __shfl_xor(s, 32);
        p4[mt] = s;
      }
      if (lk == 0) {
        #pragma unroll
        for (int mt = 0; mt < 4; ++mt)
          predp[wc*768 + (m0 + mt*16 + lr)*3 + o] = p4[mt];
      }
    }
  }
  __syncthreads();

  // ---- blend: pred[e][o] = b4 + sum_wc partials; w[s] = area[3-s]/tot -----
  if (t < TQ*3) {
    const int q = t / 3, o = t - (t/3)*3;
    const int eb = q*4;
    const size_t cbase = (((size_t)b << 16) + (q0 + q)) * 2;
    float c0 = coord[cbase + 0];
    float c1 = coord[cbase + 1];
    float ar[4];
    #pragma unroll
    for (int s = 0; s < 4; ++s) {
      float r0, r1; int ir, ic;
      rel_calc(c0, c1, s, r0, r1, ir, ic);
      ar[s] = __fadd_rn(fabsf(__fmul_rn(r0, r1)), 1e-9f);
    }
    float pe[4];
    #pragma unroll
    for (int s = 0; s < 4; ++s) {
      const int e = eb + s;
      pe[s] = b4[o] + predp[e*3 + o] + predp[768 + e*3 + o]
                    + predp[1536 + e*3 + o] + predp[2304 + e*3 + o];
    }
    float tot = ((ar[0] + ar[1]) + ar[2]) + ar[3];
    float rv = (pe[0]*ar[3] + pe[1]*ar[2] + pe[2]*ar[1] + pe[3]*ar[0]) / tot;
    out[(((size_t)b << 16) + (q0 + q))*3 + o] = rv;
  }
}

// ---------------------------------------------------------------------------
extern "C" void kernel_launch(void* const* d_in, const int* in_sizes, int n_in,
                              void* d_out, int out_size, void* d_ws, size_t ws_size,
                              hipStream_t stream)
{
  const float* feat  = (const float*)d_in[0];
  const float* coord = (const float*)d_in[1];
  const float* cell  = (const float*)d_in[2];
  const float* W0    = (const float*)d_in[3];
  const float* b0    = (const float*)d_in[4];
  const float* W1    = (const float*)d_in[5];
  const float* b1    = (const float*)d_in[6];
  const float* W2    = (const float*)d_in[7];
  const float* b2    = (const float*)d_in[8];
  const float* W3    = (const float*)d_in[9];
  const float* b3    = (const float*)d_in[10];
  const float* W4    = (const float*)d_in[11];
  const float* b4    = (const float*)d_in[12];
  float* outp = (float*)d_out;

  // ws layout: P f32 [2*2304*256] = 4,718,592 B | W image 3*8*16384 = 393,216 B
  //            | W4t f32 3*256 = 3,072 B
  float*         P    = (float*)d_ws;
  unsigned char* imgp = (unsigned char*)d_ws + 4718592;
  float*         w4tp = (float*)((unsigned char*)d_ws + 4718592 + 393216);

  hipLaunchKernelGGL(liif_precompute, dim3(2*(NPOS/4)), dim3(256), 0, stream,
                     feat, W0, b0, P);
  hipLaunchKernelGGL(liif_convert, dim3(25), dim3(256), 0, stream,
                     W1, W2, W3, W4, imgp, w4tp);
  hipLaunchKernelGGL(liif_main, dim3(2048), dim3(1024), 0, stream,
                     coord, cell, P, W0, imgp, b1, b2, b3, b4, w4tp, outp);
}